// Round 1
// baseline (6781.529 us; speedup 1.0000x reference)
//
#include <hip/hip_runtime.h>
#include <hip/hip_bf16.h>
#include <float.h>
#include <math.h>

#define BB 128
#define PP 1024
#define KNN 4

// ---------------------------------------------------------------------------
// DynamicEdgeConv: per block = 16 points of one cloud.
//  Phase 1: kNN (k=4, self included) over the cloud in feature space, fp32,
//           formula matches reference: dist = sq_i + sq_j - 2*dot.
//  Phase 2: edge MLP relu(e@W1+b1)@W2+b2, max over 4 neighbors.
// ---------------------------------------------------------------------------
template<int D, int H, int C>
__global__ __launch_bounds__(256)
void conv_kernel(const float* __restrict__ x,
                 const float* __restrict__ W1g, const float* __restrict__ b1g,
                 const float* __restrict__ W2g, const float* __restrict__ b2g,
                 float* __restrict__ out)
{
    constexpr int TI  = 16;     // points per block
    constexpr int CH  = 128;    // j-chunk
    constexpr int CHP = 132;    // padded pitch (mult of 4, not mult of 32)
    constexpr int E   = TI * KNN;
    constexpr int TD  = 2 * D;

    const int tid = threadIdx.x;
    const int b   = blockIdx.y;
    const int i0  = blockIdx.x * TI;
    const float* __restrict__ xc = x + (size_t)b * PP * D;

    __shared__ float xi[TI][D];
    __shared__ float sqi[TI];
    __shared__ __align__(16) float sqj[CH];
    __shared__ int   nidx[TI][KNN];
    __shared__ float W1s[TD * H];
    __shared__ float W2s[H * C];
    __shared__ float b1s[H];
    __shared__ float b2s[C];

    // union region: xjT | candidates | (esh + h1)
    constexpr int SZ_XJT  = D * CHP;
    constexpr int SZ_CAND = TI * 32 * KNN * 2;          // floats + ints
    constexpr int SZ_MLP  = E * TD + (E * H) / 2 + 8;   // esh fp32 + h1 bf16
    constexpr int SZ_A = SZ_XJT > SZ_CAND ? SZ_XJT : SZ_CAND;
    constexpr int SZ_U = SZ_A > SZ_MLP ? SZ_A : SZ_MLP;
    __shared__ __align__(16) float uni[SZ_U];

    float* xjT   = uni;                                   // [D][CHP]
    float* candd = uni;                                   // [TI][32][KNN]
    int*   candi = (int*)(uni + TI * 32 * KNN);           // [TI][32][KNN]
    float* esh   = uni;                                   // [E][TD]
    __hip_bfloat16* h1b = (__hip_bfloat16*)(uni + E * TD); // [E][H]

    // ---- stage weights + xi tile ----
    for (int t = tid; t < TD * H; t += 256) W1s[t] = W1g[t];
    for (int t = tid; t < H * C;  t += 256) W2s[t] = W2g[t];
    if (tid < H) b1s[tid] = b1g[tid];
    if (tid < C) b2s[tid] = b2g[tid];
    for (int t = tid; t < TI * D; t += 256) ((float*)xi)[t] = xc[(size_t)i0 * D + t];
    __syncthreads();
    if (tid < TI) {
        float s = 0.f;
        #pragma unroll
        for (int d = 0; d < D; d++) { float v = xi[tid][d]; s = fmaf(v, v, s); }
        sqi[tid] = s;
    }
    __syncthreads();

    // ---- kNN phase: 8 row-pairs x 32 j-threads ----
    const int pg = tid >> 5;          // 0..7
    const int q  = tid & 31;          // 0..31
    const int r0 = 2 * pg, r1 = r0 + 1;
    float xr0[D], xr1[D];
    #pragma unroll
    for (int d = 0; d < D; d++) { xr0[d] = xi[r0][d]; xr1[d] = xi[r1][d]; }
    const float sq0 = sqi[r0], sq1 = sqi[r1];

    float bd0[KNN], bd1[KNN];
    int   bi0[KNN], bi1[KNN];
    #pragma unroll
    for (int s = 0; s < KNN; s++) {
        bd0[s] = FLT_MAX; bd1[s] = FLT_MAX;
        bi0[s] = 0x7FFFFFFF; bi1[s] = 0x7FFFFFFF;
    }
    float wd0 = FLT_MAX, wd1 = FLT_MAX;
    int   wsl0 = 0, wsl1 = 0;

    // streaming insert: j strictly ascending per thread, so ties keep the
    // earlier (smaller) index — matches jax.lax.top_k tie-breaking.
    auto ins = [](float d, int j, float* bd, int* bi, float& wd, int& wsl) {
        if (d < wd) {
            #pragma unroll
            for (int z = 0; z < KNN; z++) if (z == wsl) { bd[z] = d; bi[z] = j; }
            float md = bd[0]; int mj = bi[0]; int ms = 0;
            #pragma unroll
            for (int z = 1; z < KNN; z++) {
                if (bd[z] > md || (bd[z] == md && bi[z] > mj)) { md = bd[z]; mj = bi[z]; ms = z; }
            }
            wd = md; wsl = ms;
        }
    };

    for (int chunk = 0; chunk < PP / CH; chunk++) {
        __syncthreads();
        const float* __restrict__ src = xc + (size_t)chunk * CH * D;
        for (int t = tid; t < CH * D; t += 256) {
            int j = t / D, d = t - j * D;
            xjT[d * CHP + j] = src[t];
        }
        __syncthreads();
        if (tid < CH) {
            float s = 0.f;
            #pragma unroll
            for (int d = 0; d < D; d++) { float v = xjT[d * CHP + tid]; s = fmaf(v, v, s); }
            sqj[tid] = s;
        }
        __syncthreads();
        {
            const int j0 = 4 * q;
            float a00 = 0.f, a01 = 0.f, a02 = 0.f, a03 = 0.f;
            float a10 = 0.f, a11 = 0.f, a12 = 0.f, a13 = 0.f;
            #pragma unroll
            for (int d = 0; d < D; d++) {
                const float4 xv = *(const float4*)&xjT[d * CHP + j0];
                a00 = fmaf(xr0[d], xv.x, a00); a01 = fmaf(xr0[d], xv.y, a01);
                a02 = fmaf(xr0[d], xv.z, a02); a03 = fmaf(xr0[d], xv.w, a03);
                a10 = fmaf(xr1[d], xv.x, a10); a11 = fmaf(xr1[d], xv.y, a11);
                a12 = fmaf(xr1[d], xv.z, a12); a13 = fmaf(xr1[d], xv.w, a13);
            }
            const float4 sjv = *(const float4*)&sqj[j0];
            const int jb = chunk * CH + j0;
            ins((sq0 + sjv.x) - 2.f * a00, jb + 0, bd0, bi0, wd0, wsl0);
            ins((sq0 + sjv.y) - 2.f * a01, jb + 1, bd0, bi0, wd0, wsl0);
            ins((sq0 + sjv.z) - 2.f * a02, jb + 2, bd0, bi0, wd0, wsl0);
            ins((sq0 + sjv.w) - 2.f * a03, jb + 3, bd0, bi0, wd0, wsl0);
            ins((sq1 + sjv.x) - 2.f * a10, jb + 0, bd1, bi1, wd1, wsl1);
            ins((sq1 + sjv.y) - 2.f * a11, jb + 1, bd1, bi1, wd1, wsl1);
            ins((sq1 + sjv.z) - 2.f * a12, jb + 2, bd1, bi1, wd1, wsl1);
            ins((sq1 + sjv.w) - 2.f * a13, jb + 3, bd1, bi1, wd1, wsl1);
        }
    }

    // ---- dump candidates, merge per row ----
    __syncthreads();   // xjT reads done; reuse union as candidate store
    #pragma unroll
    for (int s = 0; s < KNN; s++) {
        candd[(r0 * 32 + q) * KNN + s] = bd0[s];
        candi[(r0 * 32 + q) * KNN + s] = bi0[s];
        candd[(r1 * 32 + q) * KNN + s] = bd1[s];
        candi[(r1 * 32 + q) * KNN + s] = bi1[s];
    }
    __syncthreads();
    if (tid < TI) {
        float nd[KNN]; int nj[KNN];
        #pragma unroll
        for (int s = 0; s < KNN; s++) { nd[s] = FLT_MAX; nj[s] = 0x7FFFFFFF; }
        float wd = FLT_MAX; int wi = 0x7FFFFFFF; int wsl = 0;
        for (int t = 0; t < 32; t++) {
            #pragma unroll
            for (int s = 0; s < KNN; s++) {
                float dd = candd[(tid * 32 + t) * KNN + s];
                int   jj = candi[(tid * 32 + t) * KNN + s];
                bool better = (dd < wd) || (dd == wd && jj < wi);
                if (better) {
                    #pragma unroll
                    for (int z = 0; z < KNN; z++) if (z == wsl) { nd[z] = dd; nj[z] = jj; }
                    float md = nd[0]; int mj = nj[0]; int ms = 0;
                    #pragma unroll
                    for (int z = 1; z < KNN; z++) {
                        if (nd[z] > md || (nd[z] == md && nj[z] > mj)) { md = nd[z]; mj = nj[z]; ms = z; }
                    }
                    wd = md; wi = mj; wsl = ms;
                }
            }
        }
        #pragma unroll
        for (int s = 0; s < KNN; s++) nidx[tid][s] = nj[s];
    }
    __syncthreads();

    // ---- edge features e = [x_i, x_j - x_i] ----
    for (int t = tid; t < E * TD; t += 256) {
        int e = t / TD, dd = t - e * TD;
        int r = e >> 2, k = e & 3;
        int j = nidx[r][k];
        float v;
        if (dd < D) v = xi[r][dd];
        else        v = xc[(size_t)j * D + (dd - D)] - xi[r][dd - D];
        esh[e * TD + dd] = v;
    }
    __syncthreads();

    // ---- h1 = relu(e@W1 + b1) ----
    for (int t = tid; t < E * H; t += 256) {
        int e = t / H, c = t - e * H;
        float acc = 0.f;
        #pragma unroll
        for (int u = 0; u < TD; u++) acc = fmaf(esh[e * TD + u], W1s[u * H + c], acc);
        acc += b1s[c];
        h1b[e * H + c] = __float2bfloat16(fmaxf(acc, 0.f));
    }
    __syncthreads();

    // ---- h2 = h1@W2 + b2, max over 4 neighbors, store ----
    for (int t = tid; t < TI * C; t += 256) {
        int r = t / C, c = t - r * C;
        float best = -FLT_MAX;
        #pragma unroll
        for (int k = 0; k < KNN; k++) {
            float acc = 0.f;
            #pragma unroll
            for (int u = 0; u < H; u++)
                acc = fmaf(__bfloat162float(h1b[(r * KNN + k) * H + u]), W2s[u * C + c], acc);
            acc += b2s[c];
            best = fmaxf(best, acc);
        }
        out[((size_t)b * PP + i0 + r) * C + c] = best;
    }
}

// ---------------------------------------------------------------------------
// Final MLP: 64 rows per block, activations in LDS (bf16), weights staged in
// 8-row k-strips, 8x12 register tiles, fused log-softmax.
// ---------------------------------------------------------------------------
__global__ __launch_bounds__(192)
void mlp_kernel(const float* __restrict__ x1, const float* __restrict__ x2,
                const float* __restrict__ x3,
                const float* __restrict__ mW1, const float* __restrict__ mb1,
                const float* __restrict__ mW2, const float* __restrict__ mb2,
                const float* __restrict__ mW3, const float* __restrict__ mb3,
                const float* __restrict__ mW4, const float* __restrict__ mb4,
                float* __restrict__ outp)
{
    constexpr int TR = 64;
    const int tid = threadIdx.x;
    const size_t rowbase = (size_t)blockIdx.x * TR;

    __shared__ __hip_bfloat16 actA[TR * 128];
    __shared__ __hip_bfloat16 actB[TR * 264];
    __shared__ __align__(16) float Wt[8 * 268];
    __shared__ float bs[264];
    __shared__ float lsm[TR * 2];

    // load f = [x1 | x2 | x3]
    for (int t = tid; t < TR * 128; t += 192) {
        int r = t >> 7, c = t & 127;
        size_t grow = rowbase + r;
        float v;
        if (c < 32)      v = x1[grow * 32 + c];
        else if (c < 64) v = x2[grow * 32 + (c - 32)];
        else             v = x3[grow * 64 + (c - 64)];
        actA[t] = __float2bfloat16(v);
    }

    const int u  = tid;
    const int rg = u / 22, cg = u - rg * 22;   // valid when u < 176
    const int rb = rg * 8, c0 = cg * 12;

    auto run_layer = [&](const __hip_bfloat16* aIn, int PITCH, int KDIM,
                         const float* Wg, const float* bg,
                         __hip_bfloat16* aOut) {
        __syncthreads();
        for (int t = tid; t < 264; t += 192) bs[t] = bg[t];
        float acc[8][12];
        #pragma unroll
        for (int i = 0; i < 8; i++)
            #pragma unroll
            for (int j = 0; j < 12; j++) acc[i][j] = 0.f;

        for (int k0 = 0; k0 < KDIM; k0 += 8) {
            __syncthreads();
            for (int t = tid; t < 8 * 264; t += 192) {
                int kk = t / 264, c = t - kk * 264;
                Wt[kk * 268 + c] = Wg[(size_t)(k0 + kk) * 264 + c];
            }
            __syncthreads();
            if (u < 176) {
                #pragma unroll
                for (int h = 0; h < 2; h++) {
                    float a4[8][4];
                    #pragma unroll
                    for (int rr = 0; rr < 8; rr++) {
                        const __hip_bfloat162* p =
                            (const __hip_bfloat162*)&aIn[(rb + rr) * PITCH + k0 + h * 4];
                        float2 f01 = __bfloat1622float2(p[0]);
                        float2 f23 = __bfloat1622float2(p[1]);
                        a4[rr][0] = f01.x; a4[rr][1] = f01.y;
                        a4[rr][2] = f23.x; a4[rr][3] = f23.y;
                    }
                    #pragma unroll
                    for (int kk = 0; kk < 4; kk++) {
                        #pragma unroll
                        for (int cw = 0; cw < 3; cw++) {
                            const float4 w = *(const float4*)&Wt[(h * 4 + kk) * 268 + c0 + cw * 4];
                            #pragma unroll
                            for (int rr = 0; rr < 8; rr++) {
                                acc[rr][cw * 4 + 0] = fmaf(a4[rr][kk], w.x, acc[rr][cw * 4 + 0]);
                                acc[rr][cw * 4 + 1] = fmaf(a4[rr][kk], w.y, acc[rr][cw * 4 + 1]);
                                acc[rr][cw * 4 + 2] = fmaf(a4[rr][kk], w.z, acc[rr][cw * 4 + 2]);
                                acc[rr][cw * 4 + 3] = fmaf(a4[rr][kk], w.w, acc[rr][cw * 4 + 3]);
                            }
                        }
                    }
                }
            }
        }
        __syncthreads();   // all reads of aIn done -> in-place overwrite safe
        if (u < 176) {
            #pragma unroll
            for (int rr = 0; rr < 8; rr++)
                #pragma unroll
                for (int cc = 0; cc < 12; cc++) {
                    float v = acc[rr][cc] + bs[c0 + cc];
                    v = fmaxf(v, 0.f);     // relu after layers 1..3
                    aOut[(rb + rr) * 264 + (c0 + cc)] = __float2bfloat16(v);
                }
        }
    };

    run_layer(actA, 128, 128, mW1, mb1, actB);
    run_layer(actB, 264, 264, mW2, mb2, actB);
    run_layer(actB, 264, 264, mW3, mb3, actB);
    __syncthreads();

    // layer 4 (264 -> 2) + log_softmax
    if (tid < TR * 2) {
        int r = tid >> 1, c = tid & 1;
        float acc = 0.f;
        for (int k2 = 0; k2 < 264; k2++)
            acc = fmaf(__bfloat162float(actB[r * 264 + k2]), mW4[k2 * 2 + c], acc);
        lsm[r * 2 + c] = acc + mb4[c];
    }
    __syncthreads();
    if (tid < TR * 2) {
        int r = tid >> 1, c = tid & 1;
        float l0 = lsm[r * 2 + 0], l1 = lsm[r * 2 + 1];
        float m = fmaxf(l0, l1);
        float lse = m + logf(expf(l0 - m) + expf(l1 - m));
        outp[(rowbase + r) * 2 + c] = lsm[r * 2 + c] - lse;
    }
}

// ---------------------------------------------------------------------------
extern "C" void kernel_launch(void* const* d_in, const int* in_sizes, int n_in,
                              void* d_out, int out_size, void* d_ws, size_t ws_size,
                              hipStream_t stream)
{
    const float* x    = (const float*)d_in[0];
    // d_in[1] = batch (contiguous groups) -> unused
    const float* c1W1 = (const float*)d_in[2];
    const float* c1b1 = (const float*)d_in[3];
    const float* c1W2 = (const float*)d_in[4];
    const float* c1b2 = (const float*)d_in[5];
    const float* c2W1 = (const float*)d_in[6];
    const float* c2b1 = (const float*)d_in[7];
    const float* c2W2 = (const float*)d_in[8];
    const float* c2b2 = (const float*)d_in[9];
    const float* c3W1 = (const float*)d_in[10];
    const float* c3b1 = (const float*)d_in[11];
    const float* c3W2 = (const float*)d_in[12];
    const float* c3b2 = (const float*)d_in[13];
    const float* mW1  = (const float*)d_in[14];
    const float* mb1  = (const float*)d_in[15];
    const float* mW2  = (const float*)d_in[16];
    const float* mb2  = (const float*)d_in[17];
    const float* mW3  = (const float*)d_in[18];
    const float* mb3  = (const float*)d_in[19];
    const float* mW4  = (const float*)d_in[20];
    const float* mb4  = (const float*)d_in[21];

    float* x1 = (float*)d_ws;                          // [B*P,32] 16 MB
    float* x2 = x1 + (size_t)BB * PP * 32;             // [B*P,32] 16 MB
    float* x3 = x2 + (size_t)BB * PP * 32;             // [B*P,64] 32 MB

    dim3 cgrid(PP / 16, BB);
    conv_kernel<1, 32, 32><<<cgrid, 256, 0, stream>>>(x,  c1W1, c1b1, c1W2, c1b2, x1);
    conv_kernel<32, 32, 32><<<cgrid, 256, 0, stream>>>(x1, c2W1, c2b1, c2W2, c2b2, x2);
    conv_kernel<32, 64, 64><<<cgrid, 256, 0, stream>>>(x2, c3W1, c3b1, c3W2, c3b2, x3);

    mlp_kernel<<<dim3(BB * PP / 64), 192, 0, stream>>>(
        x1, x2, x3, mW1, mb1, mW2, mb2, mW3, mb3, mW4, mb4, (float*)d_out);
}

// Round 2
// 1273.677 us; speedup vs baseline: 5.3244x; 5.3244x over previous
//
#include <hip/hip_runtime.h>
#include <hip/hip_bf16.h>
#include <float.h>
#include <math.h>

#define BB 128
#define PP 1024
#define KNN 4
#define NROWS (BB * PP)

typedef __bf16 v8bf __attribute__((ext_vector_type(8)));
typedef float  v4f  __attribute__((ext_vector_type(4)));

__device__ inline unsigned short f2bs(float f) {
    __hip_bfloat16 h = __float2bfloat16(f);
    return *(unsigned short*)&h;
}

// ---------------------------------------------------------------------------
// kNN kernel: one block = 64 points of one cloud. fp32 distances, formula and
// fma ordering identical to the passing round-1 version (self-dist exactly 0,
// tie-break (dist, idx) lexicographic == jax.lax.top_k).
// Thread tile: 4 i-rows x 16 j-cols  -> 64 fma per (1+4) LDS b128 reads.
// ---------------------------------------------------------------------------
template<int D>
__global__ __launch_bounds__(256, 3)
void knn_kernel(const float* __restrict__ x, int* __restrict__ nidx)
{
    constexpr int TI = 64, CHJ = 256, CHP = 260, NCH = PP / CHJ;
    __shared__ float xiT[D * 64];                 // [d][i]
    __shared__ float sqi[TI];
    __shared__ __align__(16) float sqj[CHJ];
    constexpr int UNI = (D * CHP > 64 * 64 + 64 * 32) ? D * CHP : (64 * 64 + 64 * 32);
    __shared__ __align__(16) float uni[UNI];
    float* xjT = uni;                             // [d][CHP]
    float* candd = uni;                           // [64 slots][64 rows]
    unsigned short* candi = (unsigned short*)(uni + 64 * 64);

    const int tid = threadIdx.x;
    const int b = blockIdx.y;
    const int i0 = blockIdx.x * TI;
    const float* __restrict__ xc = x + (size_t)b * PP * D;

    if (tid < TI) {
        float s = 0.f;
        for (int d = 0; d < D; d++) {
            float v = xc[(size_t)(i0 + tid) * D + d];
            xiT[d * 64 + tid] = v;
            s = fmaf(v, v, s);
        }
        sqi[tid] = s;
    }
    __syncthreads();

    const int ti = tid & 15, tj = tid >> 4;
    float sqi4[4];
    { float4 t = *(const float4*)&sqi[4 * ti]; sqi4[0]=t.x; sqi4[1]=t.y; sqi4[2]=t.z; sqi4[3]=t.w; }

    float bd[4][4]; int bi[4][4]; float wd[4]; int wsl[4];
    #pragma unroll
    for (int r = 0; r < 4; r++) {
        #pragma unroll
        for (int z = 0; z < 4; z++) { bd[r][z] = FLT_MAX; bi[r][z] = 0x7FFF; }
        wd[r] = FLT_MAX; wsl[r] = 0;
    }

    for (int ch = 0; ch < NCH; ch++) {
        __syncthreads();
        {   // stage xjT (thread = one j row) + sqj (same fma chain as sqi)
            const float* src = xc + (size_t)(ch * CHJ + tid) * D;
            float s = 0.f;
            for (int d = 0; d < D; d++) {
                float v = src[d];
                xjT[d * CHP + tid] = v;
                s = fmaf(v, v, s);
            }
            sqj[tid] = s;
        }
        __syncthreads();

        float acc[4][16];
        #pragma unroll
        for (int r = 0; r < 4; r++)
            #pragma unroll
            for (int c = 0; c < 16; c++) acc[r][c] = 0.f;

        #pragma unroll 4
        for (int d = 0; d < D; d++) {
            float av[4];
            { float4 t = *(const float4*)&xiT[d * 64 + 4 * ti]; av[0]=t.x; av[1]=t.y; av[2]=t.z; av[3]=t.w; }
            float bv[16];
            #pragma unroll
            for (int s = 0; s < 4; s++) {
                float4 t = *(const float4*)&xjT[d * CHP + 16 * tj + 4 * s];
                bv[4*s+0]=t.x; bv[4*s+1]=t.y; bv[4*s+2]=t.z; bv[4*s+3]=t.w;
            }
            #pragma unroll
            for (int r = 0; r < 4; r++)
                #pragma unroll
                for (int c = 0; c < 16; c++)
                    acc[r][c] = fmaf(av[r], bv[c], acc[r][c]);
        }

        float sjv[16];
        #pragma unroll
        for (int s = 0; s < 4; s++) {
            float4 t = *(const float4*)&sqj[16 * tj + 4 * s];
            sjv[4*s+0]=t.x; sjv[4*s+1]=t.y; sjv[4*s+2]=t.z; sjv[4*s+3]=t.w;
        }
        const int jb = ch * CHJ + 16 * tj;
        #pragma unroll
        for (int c = 0; c < 16; c++) {
            #pragma unroll
            for (int r = 0; r < 4; r++) {
                float dist = (sqi4[r] + sjv[c]) - 2.f * acc[r][c];
                if (dist < wd[r]) {           // j ascending -> strict < keeps earlier idx
                    int j = jb + c;
                    #pragma unroll
                    for (int z = 0; z < 4; z++) if (z == wsl[r]) { bd[r][z] = dist; bi[r][z] = j; }
                    float md = bd[r][0]; int mj = bi[r][0]; int ms = 0;
                    #pragma unroll
                    for (int z = 1; z < 4; z++)
                        if (bd[r][z] > md || (bd[r][z] == md && bi[r][z] > mj)) { md = bd[r][z]; mj = bi[r][z]; ms = z; }
                    wd[r] = md; wsl[r] = ms;
                }
            }
        }
    }

    __syncthreads();   // xjT reads done; reuse union for candidates (transposed layout)
    #pragma unroll
    for (int s = 0; s < 4; s++) {
        float4 vd; vd.x = bd[0][s]; vd.y = bd[1][s]; vd.z = bd[2][s]; vd.w = bd[3][s];
        *(float4*)&candd[(4 * tj + s) * 64 + 4 * ti] = vd;
        ushort4 vi;
        vi.x = (unsigned short)bi[0][s]; vi.y = (unsigned short)bi[1][s];
        vi.z = (unsigned short)bi[2][s]; vi.w = (unsigned short)bi[3][s];
        *(ushort4*)&candi[(4 * tj + s) * 64 + 4 * ti] = vi;
    }
    __syncthreads();

    if (tid < 64) {
        float nd[4]; int nj[4];
        #pragma unroll
        for (int z = 0; z < 4; z++) { nd[z] = FLT_MAX; nj[z] = 0x7FFFFFFF; }
        float wdd = FLT_MAX; int wji = 0x7FFFFFFF; int ws = 0;
        for (int s = 0; s < 64; s++) {
            float dd = candd[s * 64 + tid];
            int jj = (int)candi[s * 64 + tid];
            bool better = (dd < wdd) || (dd == wdd && jj < wji);
            if (better) {
                #pragma unroll
                for (int z = 0; z < 4; z++) if (z == ws) { nd[z] = dd; nj[z] = jj; }
                float md = nd[0]; int mj = nj[0]; int ms = 0;
                #pragma unroll
                for (int z = 1; z < 4; z++)
                    if (nd[z] > md || (nd[z] == md && nj[z] > mj)) { md = nd[z]; mj = nj[z]; ms = z; }
                wdd = md; wji = mj; ws = ms;
            }
        }
        #pragma unroll
        for (int z = 0; z < 4; z++)
            nidx[(size_t)(b * PP + i0 + tid) * KNN + z] = b * PP + nj[z];  // absolute row
    }
}

// ---------------------------------------------------------------------------
// Edge-MLP kernel: block = 32 points (128 edges).
// h1 = [xi, xj] @ [[W1a - W1b],[W1b]] + b1  (== [xi, xj-xi] @ W1 + b1)
// out[i][c] = max_k (h1 @ W2)[i,k][c] + b2[c]
// Activations bf16, weights fp32 in LDS.
// ---------------------------------------------------------------------------
template<int D, int H, int C, typename OT>
__global__ __launch_bounds__(256, 2)
void edge_kernel(const float* __restrict__ x, const int* __restrict__ nidx,
                 const float* __restrict__ W1g, const float* __restrict__ b1g,
                 const float* __restrict__ W2g, const float* __restrict__ b2g,
                 OT* __restrict__ out)
{
    constexpr int PT = 32, NE = 128, TD = 2 * D, PE = NE + 8;
    constexpr int PH  = (H == 64) ? 72 : 36;   // h1 pitch (bf16 units)
    constexpr int HGW = (H == 64) ? 8 : 4;     // h-cols per thread in h1 GEMM
    constexpr int CW  = (C == 64) ? 8 : 4;     // c-cols per thread in h2 GEMM

    __shared__ __hip_bfloat16 xaT[TD * PE];    // [k][edge]
    __shared__ float WB[TD * H];
    __shared__ float W2s[H * C];
    __shared__ float b1s[H], b2s[C];
    __shared__ __hip_bfloat16 h1[NE * PH];
    __shared__ int nid[NE];

    const int tid = threadIdx.x;
    const size_t p0 = (size_t)blockIdx.x * PT;

    if (tid < NE) nid[tid] = nidx[p0 * KNN + tid];
    for (int t = tid; t < TD * H; t += 256) {
        int k = t / H, h = t - k * H;
        WB[t] = (k < D) ? (W1g[k * H + h] - W1g[(D + k) * H + h]) : W1g[k * H + h];
    }
    for (int t = tid; t < H * C; t += 256) W2s[t] = W2g[t];
    if (tid < H) b1s[tid] = b1g[tid];
    if (tid < C) b2s[tid] = b2g[tid];
    __syncthreads();

    // build xaT: 128 threads; thread handles edge-pair (2q, 2q+1), half of d-range
    if (tid < 128) {
        int q = tid & 63, half = tid >> 6;
        int dh = (D + 1) / 2;
        int d0 = half * dh, d1 = (D < (half + 1) * dh) ? D : (half + 1) * dh;
        const float* xi = x + (p0 + (q >> 1)) * D;          // point of edges 2q,2q+1
        const float* xj0 = x + (size_t)nid[2 * q] * D;
        const float* xj1 = x + (size_t)nid[2 * q + 1] * D;
        for (int d = d0; d < d1; d++) {
            __hip_bfloat16 v = __float2bfloat16(xi[d]);
            __hip_bfloat162 pr; pr.x = v; pr.y = v;
            *(__hip_bfloat162*)&xaT[d * PE + 2 * q] = pr;
            __hip_bfloat162 pj;
            pj.x = __float2bfloat16(xj0[d]);
            pj.y = __float2bfloat16(xj1[d]);
            *(__hip_bfloat162*)&xaT[(D + d) * PE + 2 * q] = pj;
        }
    }
    __syncthreads();

    // ---- h1 GEMM: thread = (4 edges) x (HGW h-cols) ----
    {
        const int eg = tid & 31, hg = tid >> 5;   // 32 edge-groups x 8 h-groups
        float acc[4][HGW];
        #pragma unroll
        for (int r = 0; r < 4; r++)
            #pragma unroll
            for (int j = 0; j < HGW; j++) acc[r][j] = 0.f;

        #pragma unroll 4
        for (int k = 0; k < TD; k++) {
            const __hip_bfloat162* ap = (const __hip_bfloat162*)&xaT[k * PE + 4 * eg];
            float2 a01 = __bfloat1622float2(ap[0]);
            float2 a23 = __bfloat1622float2(ap[1]);
            float av[4] = { a01.x, a01.y, a23.x, a23.y };
            float wv[HGW];
            *(float4*)&wv[0] = *(const float4*)&WB[k * H + HGW * hg];
            if constexpr (HGW == 8)
                *(float4*)&wv[4] = *(const float4*)&WB[k * H + HGW * hg + 4];
            #pragma unroll
            for (int r = 0; r < 4; r++)
                #pragma unroll
                for (int j = 0; j < HGW; j++)
                    acc[r][j] = fmaf(av[r], wv[j], acc[r][j]);
        }
        #pragma unroll
        for (int r = 0; r < 4; r++) {
            unsigned short us[HGW];
            #pragma unroll
            for (int j = 0; j < HGW; j++)
                us[j] = f2bs(fmaxf(acc[r][j] + b1s[HGW * hg + j], 0.f));
            if constexpr (HGW == 8) {
                ushort4 u0; u0.x=us[0]; u0.y=us[1]; u0.z=us[2]; u0.w=us[3];
                ushort4 u1; u1.x=us[4]; u1.y=us[5]; u1.z=us[6]; u1.w=us[7];
                *(ushort4*)&h1[(4 * eg + r) * PH + 8 * hg] = u0;
                *(ushort4*)&h1[(4 * eg + r) * PH + 8 * hg + 4] = u1;
            } else {
                ushort4 u0; u0.x=us[0]; u0.y=us[1]; u0.z=us[2]; u0.w=us[3];
                *(ushort4*)&h1[(4 * eg + r) * PH + 4 * hg] = u0;
            }
        }
    }
    __syncthreads();

    // ---- h2 GEMM + max over 4 neighbors ----
    {
        const int pt = tid & 31, cg = tid >> 5;   // 32 points x 8 c-groups
        float acc[4][CW];
        #pragma unroll
        for (int r = 0; r < 4; r++)
            #pragma unroll
            for (int c = 0; c < CW; c++) acc[r][c] = 0.f;

        if constexpr (H == 64) {
            #pragma unroll 2
            for (int kb = 0; kb < H / 8; kb++) {
                float hr[4][8];
                #pragma unroll
                for (int r = 0; r < 4; r++) {
                    const __hip_bfloat162* hp = (const __hip_bfloat162*)&h1[(4 * pt + r) * PH + 8 * kb];
                    float2 f0 = __bfloat1622float2(hp[0]);
                    float2 f1 = __bfloat1622float2(hp[1]);
                    float2 f2 = __bfloat1622float2(hp[2]);
                    float2 f3 = __bfloat1622float2(hp[3]);
                    hr[r][0]=f0.x; hr[r][1]=f0.y; hr[r][2]=f1.x; hr[r][3]=f1.y;
                    hr[r][4]=f2.x; hr[r][5]=f2.y; hr[r][6]=f3.x; hr[r][7]=f3.y;
                }
                #pragma unroll
                for (int j = 0; j < 8; j++) {
                    int k = 8 * kb + j;
                    float wv[CW];
                    *(float4*)&wv[0] = *(const float4*)&W2s[k * C + CW * cg];
                    if constexpr (CW == 8)
                        *(float4*)&wv[4] = *(const float4*)&W2s[k * C + CW * cg + 4];
                    #pragma unroll
                    for (int r = 0; r < 4; r++)
                        #pragma unroll
                        for (int c = 0; c < CW; c++)
                            acc[r][c] = fmaf(hr[r][j], wv[c], acc[r][c]);
                }
            }
        } else {
            #pragma unroll 4
            for (int k2 = 0; k2 < H; k2 += 2) {
                float2 hp[4];
                #pragma unroll
                for (int r = 0; r < 4; r++)
                    hp[r] = __bfloat1622float2(*(const __hip_bfloat162*)&h1[(4 * pt + r) * PH + k2]);
                float w0[CW], w1[CW];
                *(float4*)&w0[0] = *(const float4*)&W2s[k2 * C + CW * cg];
                *(float4*)&w1[0] = *(const float4*)&W2s[(k2 + 1) * C + CW * cg];
                #pragma unroll
                for (int r = 0; r < 4; r++)
                    #pragma unroll
                    for (int c = 0; c < CW; c++) {
                        acc[r][c] = fmaf(hp[r].x, w0[c], acc[r][c]);
                        acc[r][c] = fmaf(hp[r].y, w1[c], acc[r][c]);
                    }
            }
        }

        float res[CW];
        #pragma unroll
        for (int c = 0; c < CW; c++) {
            float m = fmaxf(fmaxf(acc[0][c], acc[1][c]), fmaxf(acc[2][c], acc[3][c]));
            res[c] = m + b2s[CW * cg + c];
        }
        if constexpr (sizeof(OT) == 4) {   // float out (CW==4)
            float4 v; v.x = res[0]; v.y = res[1]; v.z = res[2]; v.w = res[3];
            *(float4*)&out[(p0 + pt) * C + CW * cg] = v;
        } else {                            // bf16 out (CW==8)
            ushort4 u0, u1;
            u0.x=f2bs(res[0]); u0.y=f2bs(res[1]); u0.z=f2bs(res[2]); u0.w=f2bs(res[3]);
            u1.x=f2bs(res[4]); u1.y=f2bs(res[5]); u1.z=f2bs(res[6]); u1.w=f2bs(res[7]);
            *(ushort4*)&out[(p0 + pt) * C + CW * cg] = u0;
            *(ushort4*)&out[(p0 + pt) * C + CW * cg + 4] = u1;
        }
    }
}

// ---------------------------------------------------------------------------
// Weight prep: transpose + pad final-MLP weights to bf16 WT[n][k] and pad biases.
// WT1: [272][136] (K=128), WT2/WT3: [272][296] (K=264->288). Pads zeroed.
// ---------------------------------------------------------------------------
__global__ void prep_kernel(const float* __restrict__ mW1, const float* __restrict__ mW2,
                            const float* __restrict__ mW3,
                            const float* __restrict__ mb1, const float* __restrict__ mb2,
                            const float* __restrict__ mb3,
                            __hip_bfloat16* __restrict__ WT1, __hip_bfloat16* __restrict__ WT2,
                            __hip_bfloat16* __restrict__ WT3, float* __restrict__ bp)
{
    const int t0 = blockIdx.x * blockDim.x + threadIdx.x;
    const int NT = gridDim.x * blockDim.x;
    for (int i = t0; i < 272 * 136; i += NT) {
        int n = i / 136, k = i - n * 136;
        WT1[i] = (n < 264 && k < 128) ? __float2bfloat16(mW1[(size_t)k * 264 + n]) : __float2bfloat16(0.f);
    }
    for (int i = t0; i < 272 * 296; i += NT) {
        int n = i / 296, k = i - n * 296;
        WT2[i] = (n < 264 && k < 264) ? __float2bfloat16(mW2[(size_t)k * 264 + n]) : __float2bfloat16(0.f);
        WT3[i] = (n < 264 && k < 264) ? __float2bfloat16(mW3[(size_t)k * 264 + n]) : __float2bfloat16(0.f);
    }
    for (int i = t0; i < 3 * 272; i += NT) {
        int l = i / 272, n = i - l * 272;
        const float* bsrc = (l == 0) ? mb1 : (l == 1) ? mb2 : mb3;
        bp[i] = (n < 264) ? bsrc[n] : 0.f;
    }
}

// ---------------------------------------------------------------------------
// Final MLP: MFMA bf16. Block = 64 rows, 4 waves. A = WT (n as M-dim),
// B = activations (rows as N-dim) -> D frags write back as contiguous b64.
// Waves split the 17 n-tiles {w, w+4, ...}. Fused layer4 + log_softmax.
// ---------------------------------------------------------------------------
__global__ __launch_bounds__(256, 2)
void mlp_kernel(const float* __restrict__ x1, const float* __restrict__ x2,
                const __hip_bfloat16* __restrict__ x3,
                const __hip_bfloat16* __restrict__ WT1, const __hip_bfloat16* __restrict__ WT2,
                const __hip_bfloat16* __restrict__ WT3, const float* __restrict__ bp,
                const float* __restrict__ mW4, const float* __restrict__ mb4,
                float* __restrict__ outp)
{
    constexpr int KPA = 296;                       // act pitch (bf16)
    __shared__ __hip_bfloat16 act[64 * KPA];       // 37.9 KB
    __shared__ __hip_bfloat16 strip[272 * 32];     // 17.4 KB k-strip of WT
    __shared__ float W4s[264 * 2 + 2];
    __shared__ float lsm[64 * 2];

    const int tid = threadIdx.x;
    const int wv = tid >> 6, lane = tid & 63;
    const int rlane = lane & 15, ph = lane >> 4;
    const size_t row0 = (size_t)blockIdx.x * 64;

    // zero act (covers all padding), stage L1 inputs, stage W4/b4
    for (int t = tid; t < 64 * KPA / 2; t += 256) ((unsigned int*)act)[t] = 0u;
    __syncthreads();
    for (int t = tid; t < 64 * 128; t += 256) {
        int r = t >> 7, c = t & 127;
        size_t g = row0 + r;
        __hip_bfloat16 v;
        if (c < 32)       v = __float2bfloat16(x1[g * 32 + c]);
        else if (c < 64)  v = __float2bfloat16(x2[g * 32 + (c - 32)]);
        else              v = x3[g * 64 + (c - 64)];
        act[r * KPA + c] = v;
    }
    for (int t = tid; t < 530; t += 256) W4s[t] = (t < 528) ? mW4[t] : mb4[t - 528];

    const int ntc = (wv == 0) ? 5 : 4;             // n-tiles per wave (17 total)
    v4f acc[5][4];

    auto layer = [&](const __hip_bfloat16* __restrict__ WT, int KP, int NK,
                     const float* __restrict__ bias) {
        #pragma unroll
        for (int i = 0; i < 5; i++)
            #pragma unroll
            for (int rt = 0; rt < 4; rt++) acc[i][rt] = (v4f){0.f, 0.f, 0.f, 0.f};

        for (int ks = 0; ks < NK; ks++) {
            __syncthreads();
            for (int t = tid; t < 272 * 4; t += 256) {
                int n = t >> 2, s = t & 3;
                *(uint4*)&strip[n * 32 + s * 8] =
                    *(const uint4*)&WT[(size_t)n * KP + ks * 32 + s * 8];
            }
            __syncthreads();
            v8bf bf[4];
            #pragma unroll
            for (int rt = 0; rt < 4; rt++) {
                uint4 u = *(const uint4*)&act[(rt * 16 + rlane) * KPA + ks * 32 + ph * 8];
                bf[rt] = __builtin_bit_cast(v8bf, u);
            }
            #pragma unroll
            for (int i = 0; i < 5; i++) {
                if (i < ntc) {
                    int nt = wv + 4 * i;
                    uint4 ua = *(const uint4*)&strip[(nt * 16 + rlane) * 32 + ph * 8];
                    v8bf af = __builtin_bit_cast(v8bf, ua);
                    #pragma unroll
                    for (int rt = 0; rt < 4; rt++)
                        acc[i][rt] = __builtin_amdgcn_mfma_f32_16x16x32_bf16(af, bf[rt], acc[i][rt], 0, 0, 0);
                }
            }
        }
        __syncthreads();   // all reads of this layer's act done -> safe to overwrite
        #pragma unroll
        for (int i = 0; i < 5; i++) {
            if (i < ntc) {
                int nt = wv + 4 * i;
                int col0 = nt * 16 + ph * 4;
                float4 bv = *(const float4*)&bias[col0];
                #pragma unroll
                for (int rt = 0; rt < 4; rt++) {
                    int row = rt * 16 + rlane;
                    ushort4 pk;
                    pk.x = f2bs(fmaxf(acc[i][rt][0] + bv.x, 0.f));
                    pk.y = f2bs(fmaxf(acc[i][rt][1] + bv.y, 0.f));
                    pk.z = f2bs(fmaxf(acc[i][rt][2] + bv.z, 0.f));
                    pk.w = f2bs(fmaxf(acc[i][rt][3] + bv.w, 0.f));
                    *(ushort4*)&act[row * KPA + col0] = pk;
                }
            }
        }
        __syncthreads();
    };

    layer(WT1, 136, 4, bp);
    layer(WT2, 296, 9, bp + 272);
    layer(WT3, 296, 9, bp + 544);

    // layer 4 (264 -> 2) + log_softmax
    if (tid < 128) {
        int r = tid >> 1, c = tid & 1;
        float s = 0.f;
        for (int k = 0; k < 264; k++)
            s = fmaf(__bfloat162float(act[r * KPA + k]), W4s[k * 2 + c], s);
        lsm[r * 2 + c] = s + W4s[528 + c];
    }
    __syncthreads();
    if (tid < 64) {
        float l0 = lsm[tid * 2 + 0], l1 = lsm[tid * 2 + 1];
        float m = fmaxf(l0, l1);
        float lse = m + logf(expf(l0 - m) + expf(l1 - m));
        float2 o; o.x = l0 - lse; o.y = l1 - lse;
        *(float2*)&outp[(row0 + tid) * 2] = o;
    }
}

// ---------------------------------------------------------------------------
extern "C" void kernel_launch(void* const* d_in, const int* in_sizes, int n_in,
                              void* d_out, int out_size, void* d_ws, size_t ws_size,
                              hipStream_t stream)
{
    const float* x    = (const float*)d_in[0];
    const float* c1W1 = (const float*)d_in[2];
    const float* c1b1 = (const float*)d_in[3];
    const float* c1W2 = (const float*)d_in[4];
    const float* c1b2 = (const float*)d_in[5];
    const float* c2W1 = (const float*)d_in[6];
    const float* c2b1 = (const float*)d_in[7];
    const float* c2W2 = (const float*)d_in[8];
    const float* c2b2 = (const float*)d_in[9];
    const float* c3W1 = (const float*)d_in[10];
    const float* c3b1 = (const float*)d_in[11];
    const float* c3W2 = (const float*)d_in[12];
    const float* c3b2 = (const float*)d_in[13];
    const float* mW1  = (const float*)d_in[14];
    const float* mb1  = (const float*)d_in[15];
    const float* mW2  = (const float*)d_in[16];
    const float* mb2  = (const float*)d_in[17];
    const float* mW3  = (const float*)d_in[18];
    const float* mb3  = (const float*)d_in[19];
    const float* mW4  = (const float*)d_in[20];
    const float* mb4  = (const float*)d_in[21];

    // workspace carve (total ~52.8 MB)
    float* x1 = (float*)d_ws;                                   // [N,32] f32
    float* x2 = x1 + (size_t)NROWS * 32;                        // [N,32] f32
    __hip_bfloat16* x3 = (__hip_bfloat16*)(x2 + (size_t)NROWS * 32);  // [N,64] bf16
    int* nidx = (int*)(x3 + (size_t)NROWS * 64);                // [N,4] i32
    __hip_bfloat16* WT1 = (__hip_bfloat16*)(nidx + (size_t)NROWS * 4);
    __hip_bfloat16* WT2 = WT1 + 272 * 136;
    __hip_bfloat16* WT3 = WT2 + 272 * 296;
    float* bp = (float*)(WT3 + 272 * 296);                      // [3][272] f32

    prep_kernel<<<dim3(512), 256, 0, stream>>>(mW1, mW2, mW3, mb1, mb2, mb3,
                                               WT1, WT2, WT3, bp);

    dim3 kgrid(PP / 64, BB);
    dim3 egrid(NROWS / 32);

    knn_kernel<1><<<kgrid, 256, 0, stream>>>(x, nidx);
    edge_kernel<1, 32, 32, float><<<egrid, 256, 0, stream>>>(x, nidx, c1W1, c1b1, c1W2, c1b2, x1);

    knn_kernel<32><<<kgrid, 256, 0, stream>>>(x1, nidx);
    edge_kernel<32, 32, 32, float><<<egrid, 256, 0, stream>>>(x1, nidx, c2W1, c2b1, c2W2, c2b2, x2);

    knn_kernel<32><<<kgrid, 256, 0, stream>>>(x2, nidx);
    edge_kernel<32, 64, 64, __hip_bfloat16><<<egrid, 256, 0, stream>>>(x2, nidx, c3W1, c3b1, c3W2, c3b2, x3);

    mlp_kernel<<<dim3(NROWS / 64), 256, 0, stream>>>(x1, x2, x3, WT1, WT2, WT3, bp,
                                                     mW4, mb4, (float*)d_out);
}

// Round 3
// 1081.301 us; speedup vs baseline: 6.2716x; 1.1779x over previous
//
#include <hip/hip_runtime.h>
#include <hip/hip_bf16.h>
#include <float.h>
#include <math.h>

#define BB 128
#define PP 1024
#define KNN 4
#define NROWS (BB * PP)

typedef __bf16 v8bf __attribute__((ext_vector_type(8)));
typedef float  v4f  __attribute__((ext_vector_type(4)));

__device__ inline unsigned short f2bs(float f) {
    __hip_bfloat16 h = __float2bfloat16(f);
    return *(unsigned short*)&h;
}

// ---------------------------------------------------------------------------
// Pack kernel: split fp32 rows into hi/lo bf16 padded to 32 dims + row sq.
// 4 threads per row, 8 dims each -> fully coalesced 16B stores.
// ---------------------------------------------------------------------------
__global__ __launch_bounds__(256)
void pack_kernel(const float* __restrict__ src, int D,
                 __hip_bfloat16* __restrict__ xh, __hip_bfloat16* __restrict__ xl,
                 float* __restrict__ sq)
{
    const int t = blockIdx.x * 256 + threadIdx.x;     // t < NROWS*4
    const int row = t >> 2, part = t & 3;
    float v[8];
    #pragma unroll
    for (int u = 0; u < 8; u++) {
        int d = part * 8 + u;
        v[u] = (d < D) ? src[(size_t)row * D + d] : 0.f;
    }
    float s = 0.f;
    unsigned int hw[4], lw[4];
    #pragma unroll
    for (int w = 0; w < 4; w++) {
        unsigned short h2[2], l2[2];
        #pragma unroll
        for (int e = 0; e < 2; e++) {
            float x = v[2 * w + e];
            __hip_bfloat16 hb = __float2bfloat16(x);
            float hf = __bfloat162float(hb);
            __hip_bfloat16 lb = __float2bfloat16(x - hf);
            h2[e] = *(unsigned short*)&hb;
            l2[e] = *(unsigned short*)&lb;
            s = fmaf(x, x, s);
        }
        hw[w] = (unsigned int)h2[0] | ((unsigned int)h2[1] << 16);
        lw[w] = (unsigned int)l2[0] | ((unsigned int)l2[1] << 16);
    }
    s += __shfl_xor(s, 1);
    s += __shfl_xor(s, 2);
    uint4 hv; hv.x = hw[0]; hv.y = hw[1]; hv.z = hw[2]; hv.w = hw[3];
    uint4 lv; lv.x = lw[0]; lv.y = lw[1]; lv.z = lw[2]; lv.w = lw[3];
    *(uint4*)&xh[(size_t)row * 32 + part * 8] = hv;
    *(uint4*)&xl[(size_t)row * 32 + part * 8] = lv;
    if (part == 0) sq[row] = s;
}

// ---------------------------------------------------------------------------
// MFMA kNN: block = 64 i-rows of one cloud. Split-bf16 X.X^T via
// mfma_f32_16x16x32_bf16 (4 terms: ll+lh+hl+hh -> fp32-accurate dot).
// score = sqj - 2*dot (sqi is a per-row constant -> same ordering as ref dist).
// Selection: scores -> LDS, 4 threads/row streaming top-4 (ascending j,
// strict < keeps earlier index), lexicographic (score,idx) merge == lax.top_k.
// ---------------------------------------------------------------------------
__global__ __launch_bounds__(256, 4)
void knn_mfma(const __hip_bfloat16* __restrict__ xh, const __hip_bfloat16* __restrict__ xl,
              const float* __restrict__ sq, int* __restrict__ nidx)
{
    constexpr int PITCH = 129;                 // conflict-free b32 selection reads
    __shared__ __align__(16) float sc[64 * PITCH];   // 33 KB
    float* candS = sc;                          // alias after final selection
    unsigned short* candI = (unsigned short*)(sc + 16 * 64);

    const int tid = threadIdx.x;
    const int wv = tid >> 6, lane = tid & 63;
    const int lr = lane & 15, lq = lane >> 4;
    const int b = blockIdx.y, i0 = blockIdx.x * 64;
    const size_t Rb = (size_t)b * PP;

    // A-frags: 4 row-tiles, hi+lo. Lane l holds point (tile*16 + (l&15)),
    // k = (l>>4)*8 .. +8 -> one 16B load per frag, fully coalesced.
    v8bf ah[4], al[4];
    #pragma unroll
    for (int it = 0; it < 4; it++) {
        size_t g = Rb + i0 + it * 16 + lr;
        ah[it] = __builtin_bit_cast(v8bf, *(const uint4*)(xh + g * 32 + lq * 8));
        al[it] = __builtin_bit_cast(v8bf, *(const uint4*)(xl + g * 32 + lq * 8));
    }

    // selection state (thread = row r, quarter qt)
    const int r = tid & 63, qt = tid >> 6;
    float nd[4]; int nj[4]; float wd; int wsl;
    #pragma unroll
    for (int z = 0; z < 4; z++) { nd[z] = FLT_MAX; nj[z] = 0x7FFFFFFF; }
    wd = FLT_MAX; wsl = 0;

    auto ins = [&](float s, int j) {
        if (s < wd) {                       // ascending j -> strict < == lex tie-break
            #pragma unroll
            for (int z = 0; z < 4; z++) if (z == wsl) { nd[z] = s; nj[z] = j; }
            float md = nd[0]; int mj = nj[0]; int ms = 0;
            #pragma unroll
            for (int z = 1; z < 4; z++)
                if (nd[z] > md || (nd[z] == md && nj[z] > mj)) { md = nd[z]; mj = nj[z]; ms = z; }
            wd = md; wsl = ms;
        }
    };

    for (int ch = 0; ch < 8; ch++) {
        #pragma unroll
        for (int jt2 = 0; jt2 < 2; jt2++) {
            const int tl = wv * 2 + jt2;            // j-tile within chunk (0..7)
            const size_t gj = Rb + ch * 128 + tl * 16 + lr;
            v8bf bh = __builtin_bit_cast(v8bf, *(const uint4*)(xh + gj * 32 + lq * 8));
            v8bf bl = __builtin_bit_cast(v8bf, *(const uint4*)(xl + gj * 32 + lq * 8));
            const float sqv = sq[gj];               // sqj for column (l&15)
            #pragma unroll
            for (int it = 0; it < 4; it++) {
                v4f a = (v4f){0.f, 0.f, 0.f, 0.f};
                a = __builtin_amdgcn_mfma_f32_16x16x32_bf16(al[it], bl, a, 0, 0, 0);
                a = __builtin_amdgcn_mfma_f32_16x16x32_bf16(al[it], bh, a, 0, 0, 0);
                a = __builtin_amdgcn_mfma_f32_16x16x32_bf16(ah[it], bl, a, 0, 0, 0);
                a = __builtin_amdgcn_mfma_f32_16x16x32_bf16(ah[it], bh, a, 0, 0, 0);
                // D[r][c]: row = it*16 + lq*4 + m, col = tl*16 + lr
                #pragma unroll
                for (int m = 0; m < 4; m++)
                    sc[(it * 16 + lq * 4 + m) * PITCH + tl * 16 + lr] =
                        fmaf(-2.f, a[m], sqv);
            }
        }
        __syncthreads();
        // selection: thread scans 32 j of its quarter (conflict-free b32 reads)
        {
            const float* rowp = &sc[r * PITCH + qt * 32];
            const int jb = ch * 128 + qt * 32;
            #pragma unroll
            for (int u = 0; u < 32; u++) ins(rowp[u], jb + u);
        }
        __syncthreads();
    }

    // dump per-quarter candidates (alias over sc; selection reads are done)
    #pragma unroll
    for (int z = 0; z < 4; z++) {
        candS[(qt * 4 + z) * 64 + r] = nd[z];
        candI[(qt * 4 + z) * 64 + r] = (unsigned short)nj[z];
    }
    __syncthreads();

    if (tid < 64) {
        float md4[4]; int mj4[4];
        #pragma unroll
        for (int z = 0; z < 4; z++) { md4[z] = FLT_MAX; mj4[z] = 0x7FFFFFFF; }
        float wdd = FLT_MAX; int wji = 0x7FFFFFFF; int ws = 0;
        for (int s = 0; s < 16; s++) {
            float dd = candS[s * 64 + tid];
            int jj = (int)candI[s * 64 + tid];
            bool better = (dd < wdd) || (dd == wdd && jj < wji);
            if (better) {
                #pragma unroll
                for (int z = 0; z < 4; z++) if (z == ws) { md4[z] = dd; mj4[z] = jj; }
                float md = md4[0]; int mj = mj4[0]; int ms = 0;
                #pragma unroll
                for (int z = 1; z < 4; z++)
                    if (md4[z] > md || (md4[z] == md && mj4[z] > mj)) { md = md4[z]; mj = mj4[z]; ms = z; }
                wdd = md; wji = mj; ws = ms;
            }
        }
        #pragma unroll
        for (int z = 0; z < 4; z++)
            nidx[(size_t)(Rb + i0 + tid) * KNN + z] = (int)Rb + mj4[z];  // absolute row
    }
}

// ---------------------------------------------------------------------------
// Edge-MLP kernel: block = 32 points (128 edges).  (unchanged from round 2)
// ---------------------------------------------------------------------------
template<int D, int H, int C, typename OT>
__global__ __launch_bounds__(256, 2)
void edge_kernel(const float* __restrict__ x, const int* __restrict__ nidx,
                 const float* __restrict__ W1g, const float* __restrict__ b1g,
                 const float* __restrict__ W2g, const float* __restrict__ b2g,
                 OT* __restrict__ out)
{
    constexpr int PT = 32, NE = 128, TD = 2 * D, PE = NE + 8;
    constexpr int PH  = (H == 64) ? 72 : 36;
    constexpr int HGW = (H == 64) ? 8 : 4;
    constexpr int CW  = (C == 64) ? 8 : 4;

    __shared__ __hip_bfloat16 xaT[TD * PE];
    __shared__ float WB[TD * H];
    __shared__ float W2s[H * C];
    __shared__ float b1s[H], b2s[C];
    __shared__ __hip_bfloat16 h1[NE * PH];
    __shared__ int nid[NE];

    const int tid = threadIdx.x;
    const size_t p0 = (size_t)blockIdx.x * PT;

    if (tid < NE) nid[tid] = nidx[p0 * KNN + tid];
    for (int t = tid; t < TD * H; t += 256) {
        int k = t / H, h = t - k * H;
        WB[t] = (k < D) ? (W1g[k * H + h] - W1g[(D + k) * H + h]) : W1g[k * H + h];
    }
    for (int t = tid; t < H * C; t += 256) W2s[t] = W2g[t];
    if (tid < H) b1s[tid] = b1g[tid];
    if (tid < C) b2s[tid] = b2g[tid];
    __syncthreads();

    if (tid < 128) {
        int q = tid & 63, half = tid >> 6;
        int dh = (D + 1) / 2;
        int d0 = half * dh, d1 = (D < (half + 1) * dh) ? D : (half + 1) * dh;
        const float* xi = x + (p0 + (q >> 1)) * D;
        const float* xj0 = x + (size_t)nid[2 * q] * D;
        const float* xj1 = x + (size_t)nid[2 * q + 1] * D;
        for (int d = d0; d < d1; d++) {
            __hip_bfloat16 v = __float2bfloat16(xi[d]);
            __hip_bfloat162 pr; pr.x = v; pr.y = v;
            *(__hip_bfloat162*)&xaT[d * PE + 2 * q] = pr;
            __hip_bfloat162 pj;
            pj.x = __float2bfloat16(xj0[d]);
            pj.y = __float2bfloat16(xj1[d]);
            *(__hip_bfloat162*)&xaT[(D + d) * PE + 2 * q] = pj;
        }
    }
    __syncthreads();

    {
        const int eg = tid & 31, hg = tid >> 5;
        float acc[4][HGW];
        #pragma unroll
        for (int r = 0; r < 4; r++)
            #pragma unroll
            for (int j = 0; j < HGW; j++) acc[r][j] = 0.f;

        #pragma unroll 4
        for (int k = 0; k < TD; k++) {
            const __hip_bfloat162* ap = (const __hip_bfloat162*)&xaT[k * PE + 4 * eg];
            float2 a01 = __bfloat1622float2(ap[0]);
            float2 a23 = __bfloat1622float2(ap[1]);
            float av[4] = { a01.x, a01.y, a23.x, a23.y };
            float wv[HGW];
            *(float4*)&wv[0] = *(const float4*)&WB[k * H + HGW * hg];
            if constexpr (HGW == 8)
                *(float4*)&wv[4] = *(const float4*)&WB[k * H + HGW * hg + 4];
            #pragma unroll
            for (int r = 0; r < 4; r++)
                #pragma unroll
                for (int j = 0; j < HGW; j++)
                    acc[r][j] = fmaf(av[r], wv[j], acc[r][j]);
        }
        #pragma unroll
        for (int r = 0; r < 4; r++) {
            unsigned short us[HGW];
            #pragma unroll
            for (int j = 0; j < HGW; j++)
                us[j] = f2bs(fmaxf(acc[r][j] + b1s[HGW * hg + j], 0.f));
            if constexpr (HGW == 8) {
                ushort4 u0; u0.x=us[0]; u0.y=us[1]; u0.z=us[2]; u0.w=us[3];
                ushort4 u1; u1.x=us[4]; u1.y=us[5]; u1.z=us[6]; u1.w=us[7];
                *(ushort4*)&h1[(4 * eg + r) * PH + 8 * hg] = u0;
                *(ushort4*)&h1[(4 * eg + r) * PH + 8 * hg + 4] = u1;
            } else {
                ushort4 u0; u0.x=us[0]; u0.y=us[1]; u0.z=us[2]; u0.w=us[3];
                *(ushort4*)&h1[(4 * eg + r) * PH + 4 * hg] = u0;
            }
        }
    }
    __syncthreads();

    {
        const int pt = tid & 31, cg = tid >> 5;
        float acc[4][CW];
        #pragma unroll
        for (int r = 0; r < 4; r++)
            #pragma unroll
            for (int c = 0; c < CW; c++) acc[r][c] = 0.f;

        if constexpr (H == 64) {
            #pragma unroll 2
            for (int kb = 0; kb < H / 8; kb++) {
                float hr[4][8];
                #pragma unroll
                for (int r = 0; r < 4; r++) {
                    const __hip_bfloat162* hp = (const __hip_bfloat162*)&h1[(4 * pt + r) * PH + 8 * kb];
                    float2 f0 = __bfloat1622float2(hp[0]);
                    float2 f1 = __bfloat1622float2(hp[1]);
                    float2 f2 = __bfloat1622float2(hp[2]);
                    float2 f3 = __bfloat1622float2(hp[3]);
                    hr[r][0]=f0.x; hr[r][1]=f0.y; hr[r][2]=f1.x; hr[r][3]=f1.y;
                    hr[r][4]=f2.x; hr[r][5]=f2.y; hr[r][6]=f3.x; hr[r][7]=f3.y;
                }
                #pragma unroll
                for (int j = 0; j < 8; j++) {
                    int k = 8 * kb + j;
                    float wv[CW];
                    *(float4*)&wv[0] = *(const float4*)&W2s[k * C + CW * cg];
                    if constexpr (CW == 8)
                        *(float4*)&wv[4] = *(const float4*)&W2s[k * C + CW * cg + 4];
                    #pragma unroll
                    for (int r = 0; r < 4; r++)
                        #pragma unroll
                        for (int c = 0; c < CW; c++)
                            acc[r][c] = fmaf(hr[r][j], wv[c], acc[r][c]);
                }
            }
        } else {
            #pragma unroll 4
            for (int k2 = 0; k2 < H; k2 += 2) {
                float2 hp[4];
                #pragma unroll
                for (int r = 0; r < 4; r++)
                    hp[r] = __bfloat1622float2(*(const __hip_bfloat162*)&h1[(4 * pt + r) * PH + k2]);
                float w0[CW], w1[CW];
                *(float4*)&w0[0] = *(const float4*)&W2s[k2 * C + CW * cg];
                *(float4*)&w1[0] = *(const float4*)&W2s[(k2 + 1) * C + CW * cg];
                #pragma unroll
                for (int r = 0; r < 4; r++)
                    #pragma unroll
                    for (int c = 0; c < CW; c++) {
                        acc[r][c] = fmaf(hp[r].x, w0[c], acc[r][c]);
                        acc[r][c] = fmaf(hp[r].y, w1[c], acc[r][c]);
                    }
            }
        }

        float res[CW];
        #pragma unroll
        for (int c = 0; c < CW; c++) {
            float m = fmaxf(fmaxf(acc[0][c], acc[1][c]), fmaxf(acc[2][c], acc[3][c]));
            res[c] = m + b2s[CW * cg + c];
        }
        if constexpr (sizeof(OT) == 4) {
            float4 v; v.x = res[0]; v.y = res[1]; v.z = res[2]; v.w = res[3];
            *(float4*)&out[(p0 + pt) * C + CW * cg] = v;
        } else {
            ushort4 u0, u1;
            u0.x=f2bs(res[0]); u0.y=f2bs(res[1]); u0.z=f2bs(res[2]); u0.w=f2bs(res[3]);
            u1.x=f2bs(res[4]); u1.y=f2bs(res[5]); u1.z=f2bs(res[6]); u1.w=f2bs(res[7]);
            *(ushort4*)&out[(p0 + pt) * C + CW * cg] = u0;
            *(ushort4*)&out[(p0 + pt) * C + CW * cg + 4] = u1;
        }
    }
}

// ---------------------------------------------------------------------------
// Weight prep for final MLP (unchanged from round 2)
// ---------------------------------------------------------------------------
__global__ void prep_kernel(const float* __restrict__ mW1, const float* __restrict__ mW2,
                            const float* __restrict__ mW3,
                            const float* __restrict__ mb1, const float* __restrict__ mb2,
                            const float* __restrict__ mb3,
                            __hip_bfloat16* __restrict__ WT1, __hip_bfloat16* __restrict__ WT2,
                            __hip_bfloat16* __restrict__ WT3, float* __restrict__ bp)
{
    const int t0 = blockIdx.x * blockDim.x + threadIdx.x;
    const int NT = gridDim.x * blockDim.x;
    for (int i = t0; i < 272 * 136; i += NT) {
        int n = i / 136, k = i - n * 136;
        WT1[i] = (n < 264 && k < 128) ? __float2bfloat16(mW1[(size_t)k * 264 + n]) : __float2bfloat16(0.f);
    }
    for (int i = t0; i < 272 * 296; i += NT) {
        int n = i / 296, k = i - n * 296;
        WT2[i] = (n < 264 && k < 264) ? __float2bfloat16(mW2[(size_t)k * 264 + n]) : __float2bfloat16(0.f);
        WT3[i] = (n < 264 && k < 264) ? __float2bfloat16(mW3[(size_t)k * 264 + n]) : __float2bfloat16(0.f);
    }
    for (int i = t0; i < 3 * 272; i += NT) {
        int l = i / 272, n = i - l * 272;
        const float* bsrc = (l == 0) ? mb1 : (l == 1) ? mb2 : mb3;
        bp[i] = (n < 264) ? bsrc[n] : 0.f;
    }
}

// ---------------------------------------------------------------------------
// Final MLP: MFMA bf16 (unchanged from round 2)
// ---------------------------------------------------------------------------
__global__ __launch_bounds__(256, 2)
void mlp_kernel(const float* __restrict__ x1, const float* __restrict__ x2,
                const __hip_bfloat16* __restrict__ x3,
                const __hip_bfloat16* __restrict__ WT1, const __hip_bfloat16* __restrict__ WT2,
                const __hip_bfloat16* __restrict__ WT3, const float* __restrict__ bp,
                const float* __restrict__ mW4, const float* __restrict__ mb4,
                float* __restrict__ outp)
{
    constexpr int KPA = 296;
    __shared__ __hip_bfloat16 act[64 * KPA];
    __shared__ __hip_bfloat16 strip[272 * 32];
    __shared__ float W4s[264 * 2 + 2];
    __shared__ float lsm[64 * 2];

    const int tid = threadIdx.x;
    const int wv = tid >> 6, lane = tid & 63;
    const int rlane = lane & 15, ph = lane >> 4;
    const size_t row0 = (size_t)blockIdx.x * 64;

    for (int t = tid; t < 64 * KPA / 2; t += 256) ((unsigned int*)act)[t] = 0u;
    __syncthreads();
    for (int t = tid; t < 64 * 128; t += 256) {
        int r = t >> 7, c = t & 127;
        size_t g = row0 + r;
        __hip_bfloat16 v;
        if (c < 32)       v = __float2bfloat16(x1[g * 32 + c]);
        else if (c < 64)  v = __float2bfloat16(x2[g * 32 + (c - 32)]);
        else              v = x3[g * 64 + (c - 64)];
        act[r * KPA + c] = v;
    }
    for (int t = tid; t < 530; t += 256) W4s[t] = (t < 528) ? mW4[t] : mb4[t - 528];

    const int ntc = (wv == 0) ? 5 : 4;
    v4f acc[5][4];

    auto layer = [&](const __hip_bfloat16* __restrict__ WT, int KP, int NK,
                     const float* __restrict__ bias) {
        #pragma unroll
        for (int i = 0; i < 5; i++)
            #pragma unroll
            for (int rt = 0; rt < 4; rt++) acc[i][rt] = (v4f){0.f, 0.f, 0.f, 0.f};

        for (int ks = 0; ks < NK; ks++) {
            __syncthreads();
            for (int t = tid; t < 272 * 4; t += 256) {
                int n = t >> 2, s = t & 3;
                *(uint4*)&strip[n * 32 + s * 8] =
                    *(const uint4*)&WT[(size_t)n * KP + ks * 32 + s * 8];
            }
            __syncthreads();
            v8bf bf[4];
            #pragma unroll
            for (int rt = 0; rt < 4; rt++) {
                uint4 u = *(const uint4*)&act[(rt * 16 + rlane) * KPA + ks * 32 + ph * 8];
                bf[rt] = __builtin_bit_cast(v8bf, u);
            }
            #pragma unroll
            for (int i = 0; i < 5; i++) {
                if (i < ntc) {
                    int nt = wv + 4 * i;
                    uint4 ua = *(const uint4*)&strip[(nt * 16 + rlane) * 32 + ph * 8];
                    v8bf af = __builtin_bit_cast(v8bf, ua);
                    #pragma unroll
                    for (int rt = 0; rt < 4; rt++)
                        acc[i][rt] = __builtin_amdgcn_mfma_f32_16x16x32_bf16(af, bf[rt], acc[i][rt], 0, 0, 0);
                }
            }
        }
        __syncthreads();
        #pragma unroll
        for (int i = 0; i < 5; i++) {
            if (i < ntc) {
                int nt = wv + 4 * i;
                int col0 = nt * 16 + ph * 4;
                float4 bv = *(const float4*)&bias[col0];
                #pragma unroll
                for (int rt = 0; rt < 4; rt++) {
                    int row = rt * 16 + rlane;
                    ushort4 pk;
                    pk.x = f2bs(fmaxf(acc[i][rt][0] + bv.x, 0.f));
                    pk.y = f2bs(fmaxf(acc[i][rt][1] + bv.y, 0.f));
                    pk.z = f2bs(fmaxf(acc[i][rt][2] + bv.z, 0.f));
                    pk.w = f2bs(fmaxf(acc[i][rt][3] + bv.w, 0.f));
                    *(ushort4*)&act[row * KPA + col0] = pk;
                }
            }
        }
        __syncthreads();
    };

    layer(WT1, 136, 4, bp);
    layer(WT2, 296, 9, bp + 272);
    layer(WT3, 296, 9, bp + 544);

    if (tid < 128) {
        int r = tid >> 1, c = tid & 1;
        float s = 0.f;
        for (int k = 0; k < 264; k++)
            s = fmaf(__bfloat162float(act[r * KPA + k]), W4s[k * 2 + c], s);
        lsm[r * 2 + c] = s + W4s[528 + c];
    }
    __syncthreads();
    if (tid < 64) {
        float l0 = lsm[tid * 2 + 0], l1 = lsm[tid * 2 + 1];
        float m = fmaxf(l0, l1);
        float lse = m + logf(expf(l0 - m) + expf(l1 - m));
        float2 o; o.x = l0 - lse; o.y = l1 - lse;
        *(float2*)&outp[(row0 + tid) * 2] = o;
    }
}

// ---------------------------------------------------------------------------
extern "C" void kernel_launch(void* const* d_in, const int* in_sizes, int n_in,
                              void* d_out, int out_size, void* d_ws, size_t ws_size,
                              hipStream_t stream)
{
    const float* x    = (const float*)d_in[0];
    const float* c1W1 = (const float*)d_in[2];
    const float* c1b1 = (const float*)d_in[3];
    const float* c1W2 = (const float*)d_in[4];
    const float* c1b2 = (const float*)d_in[5];
    const float* c2W1 = (const float*)d_in[6];
    const float* c2b1 = (const float*)d_in[7];
    const float* c2W2 = (const float*)d_in[8];
    const float* c2b2 = (const float*)d_in[9];
    const float* c3W1 = (const float*)d_in[10];
    const float* c3b1 = (const float*)d_in[11];
    const float* c3W2 = (const float*)d_in[12];
    const float* c3b2 = (const float*)d_in[13];
    const float* mW1  = (const float*)d_in[14];
    const float* mb1  = (const float*)d_in[15];
    const float* mW2  = (const float*)d_in[16];
    const float* mb2  = (const float*)d_in[17];
    const float* mW3  = (const float*)d_in[18];
    const float* mb3  = (const float*)d_in[19];
    const float* mW4  = (const float*)d_in[20];
    const float* mb4  = (const float*)d_in[21];

    // workspace carve (~70 MB)
    float* x1 = (float*)d_ws;                                        // [N,32] f32
    float* x2 = x1 + (size_t)NROWS * 32;                             // [N,32] f32
    __hip_bfloat16* x3 = (__hip_bfloat16*)(x2 + (size_t)NROWS * 32); // [N,64] bf16
    int* nidx = (int*)(x3 + (size_t)NROWS * 64);                     // [N,4] i32
    __hip_bfloat16* WT1 = (__hip_bfloat16*)(nidx + (size_t)NROWS * 4);
    __hip_bfloat16* WT2 = WT1 + 272 * 136;
    __hip_bfloat16* WT3 = WT2 + 272 * 296;
    float* bp = (float*)(WT3 + 272 * 296);                           // [3][272] f32
    __hip_bfloat16* xph = (__hip_bfloat16*)(bp + 3 * 272);           // [N,32] bf16
    __hip_bfloat16* xpl = xph + (size_t)NROWS * 32;                  // [N,32] bf16
    float* sqw = (float*)(xpl + (size_t)NROWS * 32);                 // [N] f32

    prep_kernel<<<dim3(512), 256, 0, stream>>>(mW1, mW2, mW3, mb1, mb2, mb3,
                                               WT1, WT2, WT3, bp);

    dim3 kgrid(PP / 64, BB);
    dim3 pgrid(NROWS * 4 / 256);
    dim3 egrid(NROWS / 32);

    pack_kernel<<<pgrid, 256, 0, stream>>>(x, 1, xph, xpl, sqw);
    knn_mfma<<<kgrid, 256, 0, stream>>>(xph, xpl, sqw, nidx);
    edge_kernel<1, 32, 32, float><<<egrid, 256, 0, stream>>>(x, nidx, c1W1, c1b1, c1W2, c1b2, x1);

    pack_kernel<<<pgrid, 256, 0, stream>>>(x1, 32, xph, xpl, sqw);
    knn_mfma<<<kgrid, 256, 0, stream>>>(xph, xpl, sqw, nidx);
    edge_kernel<32, 32, 32, float><<<egrid, 256, 0, stream>>>(x1, nidx, c2W1, c2b1, c2W2, c2b2, x2);

    pack_kernel<<<pgrid, 256, 0, stream>>>(x2, 32, xph, xpl, sqw);
    knn_mfma<<<kgrid, 256, 0, stream>>>(xph, xpl, sqw, nidx);
    edge_kernel<32, 64, 64, __hip_bfloat16><<<egrid, 256, 0, stream>>>(x2, nidx, c3W1, c3b1, c3W2, c3b2, x3);

    mlp_kernel<<<dim3(NROWS / 64), 256, 0, stream>>>(x1, x2, x3, WT1, WT2, WT3, bp,
                                                     mW4, mb4, (float*)d_out);
}

// Round 5
// 1003.677 us; speedup vs baseline: 6.7567x; 1.0773x over previous
//
#include <hip/hip_runtime.h>
#include <hip/hip_bf16.h>
#include <float.h>
#include <math.h>

#define BB 128
#define PP 1024
#define KNN 4
#define NROWS (BB * PP)

typedef __bf16 v8bf __attribute__((ext_vector_type(8)));
typedef float  v4f  __attribute__((ext_vector_type(4)));

__device__ inline unsigned short f2bs(float f) {
    __hip_bfloat16 h = __float2bfloat16(f);
    return *(unsigned short*)&h;
}

// ---------------------------------------------------------------------------
// Pack kernel: split fp32 rows into hi/lo bf16 padded to 32 dims + row sq.
// ---------------------------------------------------------------------------
__global__ __launch_bounds__(256)
void pack_kernel(const float* __restrict__ src, int D,
                 __hip_bfloat16* __restrict__ xh, __hip_bfloat16* __restrict__ xl,
                 float* __restrict__ sq)
{
    const int t = blockIdx.x * 256 + threadIdx.x;     // t < NROWS*4
    const int row = t >> 2, part = t & 3;
    float v[8];
    #pragma unroll
    for (int u = 0; u < 8; u++) {
        int d = part * 8 + u;
        v[u] = (d < D) ? src[(size_t)row * D + d] : 0.f;
    }
    float s = 0.f;
    unsigned int hw[4], lw[4];
    #pragma unroll
    for (int w = 0; w < 4; w++) {
        unsigned short h2[2], l2[2];
        #pragma unroll
        for (int e = 0; e < 2; e++) {
            float x = v[2 * w + e];
            __hip_bfloat16 hb = __float2bfloat16(x);
            float hf = __bfloat162float(hb);
            __hip_bfloat16 lb = __float2bfloat16(x - hf);
            h2[e] = *(unsigned short*)&hb;
            l2[e] = *(unsigned short*)&lb;
            s = fmaf(x, x, s);
        }
        hw[w] = (unsigned int)h2[0] | ((unsigned int)h2[1] << 16);
        lw[w] = (unsigned int)l2[0] | ((unsigned int)l2[1] << 16);
    }
    s += __shfl_xor(s, 1);
    s += __shfl_xor(s, 2);
    uint4 hv; hv.x = hw[0]; hv.y = hw[1]; hv.z = hw[2]; hv.w = hw[3];
    uint4 lv; lv.x = lw[0]; lv.y = lw[1]; lv.z = lw[2]; lv.w = lw[3];
    *(uint4*)&xh[(size_t)row * 32 + part * 8] = hv;
    *(uint4*)&xl[(size_t)row * 32 + part * 8] = lv;
    if (part == 0) sq[row] = s;
}

// ---------------------------------------------------------------------------
// MFMA kNN (unchanged from round 3)
// ---------------------------------------------------------------------------
__global__ __launch_bounds__(256, 4)
void knn_mfma(const __hip_bfloat16* __restrict__ xh, const __hip_bfloat16* __restrict__ xl,
              const float* __restrict__ sq, int* __restrict__ nidx)
{
    constexpr int PITCH = 129;
    __shared__ __align__(16) float sc[64 * PITCH];
    float* candS = sc;
    unsigned short* candI = (unsigned short*)(sc + 16 * 64);

    const int tid = threadIdx.x;
    const int wv = tid >> 6, lane = tid & 63;
    const int lr = lane & 15, lq = lane >> 4;
    const int b = blockIdx.y, i0 = blockIdx.x * 64;
    const size_t Rb = (size_t)b * PP;

    v8bf ah[4], al[4];
    #pragma unroll
    for (int it = 0; it < 4; it++) {
        size_t g = Rb + i0 + it * 16 + lr;
        ah[it] = __builtin_bit_cast(v8bf, *(const uint4*)(xh + g * 32 + lq * 8));
        al[it] = __builtin_bit_cast(v8bf, *(const uint4*)(xl + g * 32 + lq * 8));
    }

    const int r = tid & 63, qt = tid >> 6;
    float nd[4]; int nj[4]; float wd; int wsl;
    #pragma unroll
    for (int z = 0; z < 4; z++) { nd[z] = FLT_MAX; nj[z] = 0x7FFFFFFF; }
    wd = FLT_MAX; wsl = 0;

    auto ins = [&](float s, int j) {
        if (s < wd) {
            #pragma unroll
            for (int z = 0; z < 4; z++) if (z == wsl) { nd[z] = s; nj[z] = j; }
            float md = nd[0]; int mj = nj[0]; int ms = 0;
            #pragma unroll
            for (int z = 1; z < 4; z++)
                if (nd[z] > md || (nd[z] == md && nj[z] > mj)) { md = nd[z]; mj = nj[z]; ms = z; }
            wd = md; wsl = ms;
        }
    };

    for (int ch = 0; ch < 8; ch++) {
        #pragma unroll
        for (int jt2 = 0; jt2 < 2; jt2++) {
            const int tl = wv * 2 + jt2;
            const size_t gj = Rb + ch * 128 + tl * 16 + lr;
            v8bf bh = __builtin_bit_cast(v8bf, *(const uint4*)(xh + gj * 32 + lq * 8));
            v8bf bl = __builtin_bit_cast(v8bf, *(const uint4*)(xl + gj * 32 + lq * 8));
            const float sqv = sq[gj];
            #pragma unroll
            for (int it = 0; it < 4; it++) {
                v4f a = (v4f){0.f, 0.f, 0.f, 0.f};
                a = __builtin_amdgcn_mfma_f32_16x16x32_bf16(al[it], bl, a, 0, 0, 0);
                a = __builtin_amdgcn_mfma_f32_16x16x32_bf16(al[it], bh, a, 0, 0, 0);
                a = __builtin_amdgcn_mfma_f32_16x16x32_bf16(ah[it], bl, a, 0, 0, 0);
                a = __builtin_amdgcn_mfma_f32_16x16x32_bf16(ah[it], bh, a, 0, 0, 0);
                #pragma unroll
                for (int m = 0; m < 4; m++)
                    sc[(it * 16 + lq * 4 + m) * PITCH + tl * 16 + lr] =
                        fmaf(-2.f, a[m], sqv);
            }
        }
        __syncthreads();
        {
            const float* rowp = &sc[r * PITCH + qt * 32];
            const int jb = ch * 128 + qt * 32;
            #pragma unroll
            for (int u = 0; u < 32; u++) ins(rowp[u], jb + u);
        }
        __syncthreads();
    }

    #pragma unroll
    for (int z = 0; z < 4; z++) {
        candS[(qt * 4 + z) * 64 + r] = nd[z];
        candI[(qt * 4 + z) * 64 + r] = (unsigned short)nj[z];
    }
    __syncthreads();

    if (tid < 64) {
        float md4[4]; int mj4[4];
        #pragma unroll
        for (int z = 0; z < 4; z++) { md4[z] = FLT_MAX; mj4[z] = 0x7FFFFFFF; }
        float wdd = FLT_MAX; int wji = 0x7FFFFFFF; int ws = 0;
        for (int s = 0; s < 16; s++) {
            float dd = candS[s * 64 + tid];
            int jj = (int)candI[s * 64 + tid];
            bool better = (dd < wdd) || (dd == wdd && jj < wji);
            if (better) {
                #pragma unroll
                for (int z = 0; z < 4; z++) if (z == ws) { md4[z] = dd; mj4[z] = jj; }
                float md = md4[0]; int mj = mj4[0]; int ms = 0;
                #pragma unroll
                for (int z = 1; z < 4; z++)
                    if (md4[z] > md || (md4[z] == md && mj4[z] > mj)) { md = md4[z]; mj = mj4[z]; ms = z; }
                wdd = md; wji = mj; ws = ms;
            }
        }
        #pragma unroll
        for (int z = 0; z < 4; z++)
            nidx[(size_t)(Rb + i0 + tid) * KNN + z] = (int)Rb + mj4[z];
    }
}

// ---------------------------------------------------------------------------
// Edge-MLP kernel (unchanged from round 3)
// ---------------------------------------------------------------------------
template<int D, int H, int C, typename OT>
__global__ __launch_bounds__(256, 2)
void edge_kernel(const float* __restrict__ x, const int* __restrict__ nidx,
                 const float* __restrict__ W1g, const float* __restrict__ b1g,
                 const float* __restrict__ W2g, const float* __restrict__ b2g,
                 OT* __restrict__ out)
{
    constexpr int PT = 32, NE = 128, TD = 2 * D, PE = NE + 8;
    constexpr int PH  = (H == 64) ? 72 : 36;
    constexpr int HGW = (H == 64) ? 8 : 4;
    constexpr int CW  = (C == 64) ? 8 : 4;

    __shared__ __hip_bfloat16 xaT[TD * PE];
    __shared__ float WB[TD * H];
    __shared__ float W2s[H * C];
    __shared__ float b1s[H], b2s[C];
    __shared__ __hip_bfloat16 h1[NE * PH];
    __shared__ int nid[NE];

    const int tid = threadIdx.x;
    const size_t p0 = (size_t)blockIdx.x * PT;

    if (tid < NE) nid[tid] = nidx[p0 * KNN + tid];
    for (int t = tid; t < TD * H; t += 256) {
        int k = t / H, h = t - k * H;
        WB[t] = (k < D) ? (W1g[k * H + h] - W1g[(D + k) * H + h]) : W1g[k * H + h];
    }
    for (int t = tid; t < H * C; t += 256) W2s[t] = W2g[t];
    if (tid < H) b1s[tid] = b1g[tid];
    if (tid < C) b2s[tid] = b2g[tid];
    __syncthreads();

    if (tid < 128) {
        int q = tid & 63, half = tid >> 6;
        int dh = (D + 1) / 2;
        int d0 = half * dh, d1 = (D < (half + 1) * dh) ? D : (half + 1) * dh;
        const float* xi = x + (p0 + (q >> 1)) * D;
        const float* xj0 = x + (size_t)nid[2 * q] * D;
        const float* xj1 = x + (size_t)nid[2 * q + 1] * D;
        for (int d = d0; d < d1; d++) {
            __hip_bfloat16 v = __float2bfloat16(xi[d]);
            __hip_bfloat162 pr; pr.x = v; pr.y = v;
            *(__hip_bfloat162*)&xaT[d * PE + 2 * q] = pr;
            __hip_bfloat162 pj;
            pj.x = __float2bfloat16(xj0[d]);
            pj.y = __float2bfloat16(xj1[d]);
            *(__hip_bfloat162*)&xaT[(D + d) * PE + 2 * q] = pj;
        }
    }
    __syncthreads();

    {
        const int eg = tid & 31, hg = tid >> 5;
        float acc[4][HGW];
        #pragma unroll
        for (int r = 0; r < 4; r++)
            #pragma unroll
            for (int j = 0; j < HGW; j++) acc[r][j] = 0.f;

        #pragma unroll 4
        for (int k = 0; k < TD; k++) {
            const __hip_bfloat162* ap = (const __hip_bfloat162*)&xaT[k * PE + 4 * eg];
            float2 a01 = __bfloat1622float2(ap[0]);
            float2 a23 = __bfloat1622float2(ap[1]);
            float av[4] = { a01.x, a01.y, a23.x, a23.y };
            float wv[HGW];
            *(float4*)&wv[0] = *(const float4*)&WB[k * H + HGW * hg];
            if constexpr (HGW == 8)
                *(float4*)&wv[4] = *(const float4*)&WB[k * H + HGW * hg + 4];
            #pragma unroll
            for (int r = 0; r < 4; r++)
                #pragma unroll
                for (int j = 0; j < HGW; j++)
                    acc[r][j] = fmaf(av[r], wv[j], acc[r][j]);
        }
        #pragma unroll
        for (int r = 0; r < 4; r++) {
            unsigned short us[HGW];
            #pragma unroll
            for (int j = 0; j < HGW; j++)
                us[j] = f2bs(fmaxf(acc[r][j] + b1s[HGW * hg + j], 0.f));
            if constexpr (HGW == 8) {
                ushort4 u0; u0.x=us[0]; u0.y=us[1]; u0.z=us[2]; u0.w=us[3];
                ushort4 u1; u1.x=us[4]; u1.y=us[5]; u1.z=us[6]; u1.w=us[7];
                *(ushort4*)&h1[(4 * eg + r) * PH + 8 * hg] = u0;
                *(ushort4*)&h1[(4 * eg + r) * PH + 8 * hg + 4] = u1;
            } else {
                ushort4 u0; u0.x=us[0]; u0.y=us[1]; u0.z=us[2]; u0.w=us[3];
                *(ushort4*)&h1[(4 * eg + r) * PH + 4 * hg] = u0;
            }
        }
    }
    __syncthreads();

    {
        const int pt = tid & 31, cg = tid >> 5;
        float acc[4][CW];
        #pragma unroll
        for (int r = 0; r < 4; r++)
            #pragma unroll
            for (int c = 0; c < CW; c++) acc[r][c] = 0.f;

        if constexpr (H == 64) {
            #pragma unroll 2
            for (int kb = 0; kb < H / 8; kb++) {
                float hr[4][8];
                #pragma unroll
                for (int r = 0; r < 4; r++) {
                    const __hip_bfloat162* hp = (const __hip_bfloat162*)&h1[(4 * pt + r) * PH + 8 * kb];
                    float2 f0 = __bfloat1622float2(hp[0]);
                    float2 f1 = __bfloat1622float2(hp[1]);
                    float2 f2 = __bfloat1622float2(hp[2]);
                    float2 f3 = __bfloat1622float2(hp[3]);
                    hr[r][0]=f0.x; hr[r][1]=f0.y; hr[r][2]=f1.x; hr[r][3]=f1.y;
                    hr[r][4]=f2.x; hr[r][5]=f2.y; hr[r][6]=f3.x; hr[r][7]=f3.y;
                }
                #pragma unroll
                for (int j = 0; j < 8; j++) {
                    int k = 8 * kb + j;
                    float wv[CW];
                    *(float4*)&wv[0] = *(const float4*)&W2s[k * C + CW * cg];
                    if constexpr (CW == 8)
                        *(float4*)&wv[4] = *(const float4*)&W2s[k * C + CW * cg + 4];
                    #pragma unroll
                    for (int r = 0; r < 4; r++)
                        #pragma unroll
                        for (int c = 0; c < CW; c++)
                            acc[r][c] = fmaf(hr[r][j], wv[c], acc[r][c]);
                }
            }
        } else {
            #pragma unroll 4
            for (int k2 = 0; k2 < H; k2 += 2) {
                float2 hp[4];
                #pragma unroll
                for (int r = 0; r < 4; r++)
                    hp[r] = __bfloat1622float2(*(const __hip_bfloat162*)&h1[(4 * pt + r) * PH + k2]);
                float w0[CW], w1[CW];
                *(float4*)&w0[0] = *(const float4*)&W2s[k2 * C + CW * cg];
                *(float4*)&w1[0] = *(const float4*)&W2s[(k2 + 1) * C + CW * cg];
                #pragma unroll
                for (int r = 0; r < 4; r++)
                    #pragma unroll
                    for (int c = 0; c < CW; c++) {
                        acc[r][c] = fmaf(hp[r].x, w0[c], acc[r][c]);
                        acc[r][c] = fmaf(hp[r].y, w1[c], acc[r][c]);
                    }
            }
        }

        float res[CW];
        #pragma unroll
        for (int c = 0; c < CW; c++) {
            float m = fmaxf(fmaxf(acc[0][c], acc[1][c]), fmaxf(acc[2][c], acc[3][c]));
            res[c] = m + b2s[CW * cg + c];
        }
        if constexpr (sizeof(OT) == 4) {
            float4 v; v.x = res[0]; v.y = res[1]; v.z = res[2]; v.w = res[3];
            *(float4*)&out[(p0 + pt) * C + CW * cg] = v;
        } else {
            ushort4 u0, u1;
            u0.x=f2bs(res[0]); u0.y=f2bs(res[1]); u0.z=f2bs(res[2]); u0.w=f2bs(res[3]);
            u1.x=f2bs(res[4]); u1.y=f2bs(res[5]); u1.z=f2bs(res[6]); u1.w=f2bs(res[7]);
            *(ushort4*)&out[(p0 + pt) * C + CW * cg] = u0;
            *(ushort4*)&out[(p0 + pt) * C + CW * cg + 4] = u1;
        }
    }
}

// ---------------------------------------------------------------------------
// Weight prep for final MLP (unchanged)
// ---------------------------------------------------------------------------
__global__ void prep_kernel(const float* __restrict__ mW1, const float* __restrict__ mW2,
                            const float* __restrict__ mW3,
                            const float* __restrict__ mb1, const float* __restrict__ mb2,
                            const float* __restrict__ mb3,
                            __hip_bfloat16* __restrict__ WT1, __hip_bfloat16* __restrict__ WT2,
                            __hip_bfloat16* __restrict__ WT3, float* __restrict__ bp)
{
    const int t0 = blockIdx.x * blockDim.x + threadIdx.x;
    const int NT = gridDim.x * blockDim.x;
    for (int i = t0; i < 272 * 136; i += NT) {
        int n = i / 136, k = i - n * 136;
        WT1[i] = (n < 264 && k < 128) ? __float2bfloat16(mW1[(size_t)k * 264 + n]) : __float2bfloat16(0.f);
    }
    for (int i = t0; i < 272 * 296; i += NT) {
        int n = i / 296, k = i - n * 296;
        WT2[i] = (n < 264 && k < 264) ? __float2bfloat16(mW2[(size_t)k * 264 + n]) : __float2bfloat16(0.f);
        WT3[i] = (n < 264 && k < 264) ? __float2bfloat16(mW3[(size_t)k * 264 + n]) : __float2bfloat16(0.f);
    }
    for (int i = t0; i < 3 * 272; i += NT) {
        int l = i / 272, n = i - l * 272;
        const float* bsrc = (l == 0) ? mb1 : (l == 1) ? mb2 : mb3;
        bp[i] = (n < 264) ? bsrc[n] : 0.f;
    }
}

// ---------------------------------------------------------------------------
// Final MLP v2b: weight A-frags loaded DIRECTLY from global (L2-resident) —
// no strip LDS, no k-loop barriers. FIX vs v2: one __syncthreads() between
// the initial act staging and layer 1's act reads (the round-4 race).
// ---------------------------------------------------------------------------
__global__ __launch_bounds__(256, 3)
void mlp_kernel(const float* __restrict__ x1, const float* __restrict__ x2,
                const __hip_bfloat16* __restrict__ x3,
                const __hip_bfloat16* __restrict__ WT1, const __hip_bfloat16* __restrict__ WT2,
                const __hip_bfloat16* __restrict__ WT3, const float* __restrict__ bp,
                const float* __restrict__ mW4, const float* __restrict__ mb4,
                float* __restrict__ outp)
{
    constexpr int KPA = 296;                    // pitch 148 words ≡ 20 mod 32 -> 2-way max
    __shared__ __hip_bfloat16 act[64 * KPA];    // 37.9 KB
    __shared__ float W4s[264 * 2 + 2];
    __shared__ float lsm[64 * 2];

    const int tid = threadIdx.x;
    const int wv = tid >> 6, lane = tid & 63;
    const int rlane = lane & 15, ph = lane >> 4;
    const size_t row0 = (size_t)blockIdx.x * 64;

    // zero act (covers padding), stage L1 inputs, stage W4/b4
    for (int t = tid; t < 64 * KPA / 2; t += 256) ((unsigned int*)act)[t] = 0u;
    __syncthreads();
    for (int t = tid; t < 64 * 128; t += 256) {
        int r = t >> 7, c = t & 127;
        size_t g = row0 + r;
        __hip_bfloat16 v;
        if (c < 32)       v = __float2bfloat16(x1[g * 32 + c]);
        else if (c < 64)  v = __float2bfloat16(x2[g * 32 + (c - 32)]);
        else              v = x3[g * 64 + (c - 64)];
        act[r * KPA + c] = v;
    }
    for (int t = tid; t < 530; t += 256) W4s[t] = (t < 528) ? mW4[t] : mb4[t - 528];
    __syncthreads();   // <-- FIX: staging writes must complete before layer-1 act reads

    const int ntc = (wv == 0) ? 5 : 4;          // 17 n-tiles over 4 waves
    v4f acc[5][4];

    auto layer = [&](const __hip_bfloat16* __restrict__ WT, int KP, int NK,
                     const float* __restrict__ bias) {
        #pragma unroll
        for (int i = 0; i < 5; i++)
            #pragma unroll
            for (int rt = 0; rt < 4; rt++) acc[i][rt] = (v4f){0.f, 0.f, 0.f, 0.f};

        // no barriers in the k-loop: act read-only, weights straight from L2
        for (int ks = 0; ks < NK; ks++) {
            v8bf bf[4];
            #pragma unroll
            for (int rt = 0; rt < 4; rt++) {
                uint4 u = *(const uint4*)&act[(rt * 16 + rlane) * KPA + ks * 32 + ph * 8];
                bf[rt] = __builtin_bit_cast(v8bf, u);
            }
            #pragma unroll
            for (int i = 0; i < 5; i++) {
                if (i < ntc) {
                    int nt = wv + 4 * i;
                    uint4 ua = *(const uint4*)(WT + (size_t)(nt * 16 + rlane) * KP + ks * 32 + ph * 8);
                    v8bf af = __builtin_bit_cast(v8bf, ua);
                    #pragma unroll
                    for (int rt = 0; rt < 4; rt++)
                        acc[i][rt] = __builtin_amdgcn_mfma_f32_16x16x32_bf16(af, bf[rt], acc[i][rt], 0, 0, 0);
                }
            }
        }
        __syncthreads();   // all act reads done -> safe to overwrite in place
        #pragma unroll
        for (int i = 0; i < 5; i++) {
            if (i < ntc) {
                int nt = wv + 4 * i;
                int col0 = nt * 16 + ph * 4;
                float4 bv = *(const float4*)&bias[col0];
                #pragma unroll
                for (int rt = 0; rt < 4; rt++) {
                    int row = rt * 16 + rlane;
                    ushort4 pk;
                    pk.x = f2bs(fmaxf(acc[i][rt][0] + bv.x, 0.f));
                    pk.y = f2bs(fmaxf(acc[i][rt][1] + bv.y, 0.f));
                    pk.z = f2bs(fmaxf(acc[i][rt][2] + bv.z, 0.f));
                    pk.w = f2bs(fmaxf(acc[i][rt][3] + bv.w, 0.f));
                    *(ushort4*)&act[row * KPA + col0] = pk;
                }
            }
        }
        __syncthreads();
    };

    layer(WT1, 136, 4, bp);
    layer(WT2, 296, 9, bp + 272);
    layer(WT3, 296, 9, bp + 544);

    // layer 4 (264 -> 2) + log_softmax
    if (tid < 128) {
        int r = tid >> 1, c = tid & 1;
        float s = 0.f;
        for (int k = 0; k < 264; k++)
            s = fmaf(__bfloat162float(act[r * KPA + k]), W4s[k * 2 + c], s);
        lsm[r * 2 + c] = s + W4s[528 + c];
    }
    __syncthreads();
    if (tid < 64) {
        float l0 = lsm[tid * 2 + 0], l1 = lsm[tid * 2 + 1];
        float m = fmaxf(l0, l1);
        float lse = m + logf(expf(l0 - m) + expf(l1 - m));
        float2 o; o.x = l0 - lse; o.y = l1 - lse;
        *(float2*)&outp[(row0 + tid) * 2] = o;
    }
}

// ---------------------------------------------------------------------------
extern "C" void kernel_launch(void* const* d_in, const int* in_sizes, int n_in,
                              void* d_out, int out_size, void* d_ws, size_t ws_size,
                              hipStream_t stream)
{
    const float* x    = (const float*)d_in[0];
    const float* c1W1 = (const float*)d_in[2];
    const float* c1b1 = (const float*)d_in[3];
    const float* c1W2 = (const float*)d_in[4];
    const float* c1b2 = (const float*)d_in[5];
    const float* c2W1 = (const float*)d_in[6];
    const float* c2b1 = (const float*)d_in[7];
    const float* c2W2 = (const float*)d_in[8];
    const float* c2b2 = (const float*)d_in[9];
    const float* c3W1 = (const float*)d_in[10];
    const float* c3b1 = (const float*)d_in[11];
    const float* c3W2 = (const float*)d_in[12];
    const float* c3b2 = (const float*)d_in[13];
    const float* mW1  = (const float*)d_in[14];
    const float* mb1  = (const float*)d_in[15];
    const float* mW2  = (const float*)d_in[16];
    const float* mb2  = (const float*)d_in[17];
    const float* mW3  = (const float*)d_in[18];
    const float* mb3  = (const float*)d_in[19];
    const float* mW4  = (const float*)d_in[20];
    const float* mb4  = (const float*)d_in[21];

    // workspace carve (~70 MB)
    float* x1 = (float*)d_ws;                                        // [N,32] f32
    float* x2 = x1 + (size_t)NROWS * 32;                             // [N,32] f32
    __hip_bfloat16* x3 = (__hip_bfloat16*)(x2 + (size_t)NROWS * 32); // [N,64] bf16
    int* nidx = (int*)(x3 + (size_t)NROWS * 64);                     // [N,4] i32
    __hip_bfloat16* WT1 = (__hip_bfloat16*)(nidx + (size_t)NROWS * 4);
    __hip_bfloat16* WT2 = WT1 + 272 * 136;
    __hip_bfloat16* WT3 = WT2 + 272 * 296;
    float* bp = (float*)(WT3 + 272 * 296);                           // [3][272] f32
    __hip_bfloat16* xph = (__hip_bfloat16*)(bp + 3 * 272);           // [N,32] bf16
    __hip_bfloat16* xpl = xph + (size_t)NROWS * 32;                  // [N,32] bf16
    float* sqw = (float*)(xpl + (size_t)NROWS * 32);                 // [N] f32

    prep_kernel<<<dim3(512), 256, 0, stream>>>(mW1, mW2, mW3, mb1, mb2, mb3,
                                               WT1, WT2, WT3, bp);

    dim3 kgrid(PP / 64, BB);
    dim3 pgrid(NROWS * 4 / 256);
    dim3 egrid(NROWS / 32);

    pack_kernel<<<pgrid, 256, 0, stream>>>(x, 1, xph, xpl, sqw);
    knn_mfma<<<kgrid, 256, 0, stream>>>(xph, xpl, sqw, nidx);
    edge_kernel<1, 32, 32, float><<<egrid, 256, 0, stream>>>(x, nidx, c1W1, c1b1, c1W2, c1b2, x1);

    pack_kernel<<<pgrid, 256, 0, stream>>>(x1, 32, xph, xpl, sqw);
    knn_mfma<<<kgrid, 256, 0, stream>>>(xph, xpl, sqw, nidx);
    edge_kernel<32, 32, 32, float><<<egrid, 256, 0, stream>>>(x1, nidx, c2W1, c2b1, c2W2, c2b2, x2);

    pack_kernel<<<pgrid, 256, 0, stream>>>(x2, 32, xph, xpl, sqw);
    knn_mfma<<<kgrid, 256, 0, stream>>>(xph, xpl, sqw, nidx);
    edge_kernel<32, 64, 64, __hip_bfloat16><<<egrid, 256, 0, stream>>>(x2, nidx, c3W1, c3b1, c3W2, c3b2, x3);

    mlp_kernel<<<dim3(NROWS / 64), 256, 0, stream>>>(x1, x2, x3, WT1, WT2, WT3, bp,
                                                     mW4, mb4, (float*)d_out);
}

// Round 7
// 800.830 us; speedup vs baseline: 8.4681x; 1.2533x over previous
//
#include <hip/hip_runtime.h>
#include <hip/hip_bf16.h>
#include <float.h>
#include <math.h>

#define BB 128
#define PP 1024
#define KNN 4
#define NROWS (BB * PP)

typedef __bf16 v8bf __attribute__((ext_vector_type(8)));
typedef float  v4f  __attribute__((ext_vector_type(4)));

__device__ inline unsigned short f2bs(float f) {
    __hip_bfloat16 h = __float2bfloat16(f);
    return *(unsigned short*)&h;
}

// bf16 pair (packed in u32) -> two f32, bit-exact, no struct types
__device__ inline float bflo(unsigned u) { return __builtin_bit_cast(float, u << 16); }
__device__ inline float bfhi(unsigned u) { return __builtin_bit_cast(float, u & 0xFFFF0000u); }

// ---------------------------------------------------------------------------
// Pack kernel: split fp32 rows into hi/lo bf16 padded to 32 dims + row sq.
// ---------------------------------------------------------------------------
__global__ __launch_bounds__(256)
void pack_kernel(const float* __restrict__ src, int D,
                 __hip_bfloat16* __restrict__ xh, __hip_bfloat16* __restrict__ xl,
                 float* __restrict__ sq)
{
    const int t = blockIdx.x * 256 + threadIdx.x;     // t < NROWS*4
    const int row = t >> 2, part = t & 3;
    float v[8];
    #pragma unroll
    for (int u = 0; u < 8; u++) {
        int d = part * 8 + u;
        v[u] = (d < D) ? src[(size_t)row * D + d] : 0.f;
    }
    float s = 0.f;
    unsigned int hw[4], lw[4];
    #pragma unroll
    for (int w = 0; w < 4; w++) {
        unsigned short h2[2], l2[2];
        #pragma unroll
        for (int e = 0; e < 2; e++) {
            float x = v[2 * w + e];
            __hip_bfloat16 hb = __float2bfloat16(x);
            float hf = __bfloat162float(hb);
            __hip_bfloat16 lb = __float2bfloat16(x - hf);
            h2[e] = *(unsigned short*)&hb;
            l2[e] = *(unsigned short*)&lb;
            s = fmaf(x, x, s);
        }
        hw[w] = (unsigned int)h2[0] | ((unsigned int)h2[1] << 16);
        lw[w] = (unsigned int)l2[0] | ((unsigned int)l2[1] << 16);
    }
    s += __shfl_xor(s, 1);
    s += __shfl_xor(s, 2);
    uint4 hv; hv.x = hw[0]; hv.y = hw[1]; hv.z = hw[2]; hv.w = hw[3];
    uint4 lv; lv.x = lw[0]; lv.y = lw[1]; lv.z = lw[2]; lv.w = lw[3];
    *(uint4*)&xh[(size_t)row * 32 + part * 8] = hv;
    *(uint4*)&xl[(size_t)row * 32 + part * 8] = lv;
    if (part == 0) sq[row] = s;
}

// ---------------------------------------------------------------------------
// MFMA kNN v3: split-bf16 X.X^T via mfma (unchanged math), selection:
// branchless sorted 4-slot chain on u64 keys key=(ord(score)<<32)|j.
// Keys are unique -> total order; lex (score,idx) == lax.top_k tie-break.
// ---------------------------------------------------------------------------
__global__ __launch_bounds__(256, 4)
void knn_mfma(const __hip_bfloat16* __restrict__ xh, const __hip_bfloat16* __restrict__ xl,
              const float* __restrict__ sq, int* __restrict__ nidx)
{
    constexpr int PITCH = 129;                       // conflict-free b32 selection reads
    __shared__ __align__(16) float sc[64 * PITCH];   // 33 KB
    unsigned long long* cand64 = (unsigned long long*)sc;  // [16][64] alias, used at end

    const int tid = threadIdx.x;
    const int wv = tid >> 6, lane = tid & 63;
    const int lr = lane & 15, lq = lane >> 4;
    const int b = blockIdx.y, i0 = blockIdx.x * 64;
    const size_t Rb = (size_t)b * PP;

    v8bf ah[4], al[4];
    #pragma unroll
    for (int it = 0; it < 4; it++) {
        size_t g = Rb + i0 + it * 16 + lr;
        ah[it] = __builtin_bit_cast(v8bf, *(const uint4*)(xh + g * 32 + lq * 8));
        al[it] = __builtin_bit_cast(v8bf, *(const uint4*)(xl + g * 32 + lq * 8));
    }

    const int r = tid & 63, qt = tid >> 6;
    unsigned long long k0 = ~0ull, k1 = ~0ull, k2 = ~0ull, k3 = ~0ull;

    for (int ch = 0; ch < 8; ch++) {
        #pragma unroll
        for (int jt2 = 0; jt2 < 2; jt2++) {
            const int tl = wv * 2 + jt2;
            const size_t gj = Rb + ch * 128 + tl * 16 + lr;
            v8bf bh = __builtin_bit_cast(v8bf, *(const uint4*)(xh + gj * 32 + lq * 8));
            v8bf bl = __builtin_bit_cast(v8bf, *(const uint4*)(xl + gj * 32 + lq * 8));
            const float sqv = sq[gj];
            #pragma unroll
            for (int it = 0; it < 4; it++) {
                v4f a = (v4f){0.f, 0.f, 0.f, 0.f};
                a = __builtin_amdgcn_mfma_f32_16x16x32_bf16(al[it], bl, a, 0, 0, 0);
                a = __builtin_amdgcn_mfma_f32_16x16x32_bf16(al[it], bh, a, 0, 0, 0);
                a = __builtin_amdgcn_mfma_f32_16x16x32_bf16(ah[it], bl, a, 0, 0, 0);
                a = __builtin_amdgcn_mfma_f32_16x16x32_bf16(ah[it], bh, a, 0, 0, 0);
                #pragma unroll
                for (int m = 0; m < 4; m++)
                    sc[(it * 16 + lq * 4 + m) * PITCH + tl * 16 + lr] =
                        fmaf(-2.f, a[m], sqv);
            }
        }
        __syncthreads();
        // selection: thread scans 32 j of its quarter. Branchless u64 chain:
        // slots k0<=k1<=k2<=k3; new key pushes down; displaced k3 drops out.
        {
            const float* rowp = &sc[r * PITCH + qt * 32];
            const int jb = ch * 128 + qt * 32;
            #pragma unroll
            for (int u = 0; u < 32; u++) {
                float s = rowp[u];
                unsigned ub = __builtin_bit_cast(unsigned, s);
                unsigned mm = (unsigned)((int)ub >> 31);
                unsigned ord = ub ^ (mm | 0x80000000u);
                unsigned long long key =
                    ((unsigned long long)ord << 32) | (unsigned)(jb + u);
                unsigned long long t; bool c;
                c = key < k0; t = c ? key : k0; key = c ? k0 : key; k0 = t;
                c = key < k1; t = c ? key : k1; key = c ? k1 : key; k1 = t;
                c = key < k2; t = c ? key : k2; key = c ? k2 : key; k2 = t;
                c = key < k3; k3 = c ? key : k3;
            }
        }
        __syncthreads();
    }

    // dump per-quarter candidates (alias over sc; all selection reads done)
    cand64[(qt * 4 + 0) * 64 + r] = k0;
    cand64[(qt * 4 + 1) * 64 + r] = k1;
    cand64[(qt * 4 + 2) * 64 + r] = k2;
    cand64[(qt * 4 + 3) * 64 + r] = k3;
    __syncthreads();

    if (tid < 64) {
        unsigned long long m0 = ~0ull, m1 = ~0ull, m2 = ~0ull, m3 = ~0ull;
        #pragma unroll
        for (int s2 = 0; s2 < 16; s2++) {
            unsigned long long key = cand64[s2 * 64 + tid];
            unsigned long long t; bool c;
            c = key < m0; t = c ? key : m0; key = c ? m0 : key; m0 = t;
            c = key < m1; t = c ? key : m1; key = c ? m1 : key; m1 = t;
            c = key < m2; t = c ? key : m2; key = c ? m2 : key; m2 = t;
            c = key < m3; m3 = c ? key : m3;
        }
        const int base = (int)Rb;
        int* op = nidx + (size_t)(Rb + i0 + tid) * KNN;
        op[0] = base + (int)((unsigned)m0 & 1023u);
        op[1] = base + (int)((unsigned)m1 & 1023u);
        op[2] = base + (int)((unsigned)m2 & 1023u);
        op[3] = base + (int)((unsigned)m3 & 1023u);
    }
}

// ---------------------------------------------------------------------------
// Edge-MLP kernel (unchanged from round 5)
// ---------------------------------------------------------------------------
template<int D, int H, int C, typename OT>
__global__ __launch_bounds__(256, 2)
void edge_kernel(const float* __restrict__ x, const int* __restrict__ nidx,
                 const float* __restrict__ W1g, const float* __restrict__ b1g,
                 const float* __restrict__ W2g, const float* __restrict__ b2g,
                 OT* __restrict__ out)
{
    constexpr int PT = 32, NE = 128, TD = 2 * D, PE = NE + 8;
    constexpr int PH  = (H == 64) ? 72 : 36;
    constexpr int HGW = (H == 64) ? 8 : 4;
    constexpr int CW  = (C == 64) ? 8 : 4;

    __shared__ __hip_bfloat16 xaT[TD * PE];
    __shared__ float WB[TD * H];
    __shared__ float W2s[H * C];
    __shared__ float b1s[H], b2s[C];
    __shared__ __hip_bfloat16 h1[NE * PH];
    __shared__ int nid[NE];

    const int tid = threadIdx.x;
    const size_t p0 = (size_t)blockIdx.x * PT;

    if (tid < NE) nid[tid] = nidx[p0 * KNN + tid];
    for (int t = tid; t < TD * H; t += 256) {
        int k = t / H, h = t - k * H;
        WB[t] = (k < D) ? (W1g[k * H + h] - W1g[(D + k) * H + h]) : W1g[k * H + h];
    }
    for (int t = tid; t < H * C; t += 256) W2s[t] = W2g[t];
    if (tid < H) b1s[tid] = b1g[tid];
    if (tid < C) b2s[tid] = b2g[tid];
    __syncthreads();

    if (tid < 128) {
        int q = tid & 63, half = tid >> 6;
        int dh = (D + 1) / 2;
        int d0 = half * dh, d1 = (D < (half + 1) * dh) ? D : (half + 1) * dh;
        const float* xi = x + (p0 + (q >> 1)) * D;
        const float* xj0 = x + (size_t)nid[2 * q] * D;
        const float* xj1 = x + (size_t)nid[2 * q + 1] * D;
        for (int d = d0; d < d1; d++) {
            __hip_bfloat16 v = __float2bfloat16(xi[d]);
            __hip_bfloat162 pr; pr.x = v; pr.y = v;
            *(__hip_bfloat162*)&xaT[d * PE + 2 * q] = pr;
            __hip_bfloat162 pj;
            pj.x = __float2bfloat16(xj0[d]);
            pj.y = __float2bfloat16(xj1[d]);
            *(__hip_bfloat162*)&xaT[(D + d) * PE + 2 * q] = pj;
        }
    }
    __syncthreads();

    {
        const int eg = tid & 31, hg = tid >> 5;
        float acc[4][HGW];
        #pragma unroll
        for (int r = 0; r < 4; r++)
            #pragma unroll
            for (int j = 0; j < HGW; j++) acc[r][j] = 0.f;

        #pragma unroll 4
        for (int k = 0; k < TD; k++) {
            const __hip_bfloat162* ap = (const __hip_bfloat162*)&xaT[k * PE + 4 * eg];
            float2 a01 = __bfloat1622float2(ap[0]);
            float2 a23 = __bfloat1622float2(ap[1]);
            float av[4] = { a01.x, a01.y, a23.x, a23.y };
            float wv[HGW];
            *(float4*)&wv[0] = *(const float4*)&WB[k * H + HGW * hg];
            if constexpr (HGW == 8)
                *(float4*)&wv[4] = *(const float4*)&WB[k * H + HGW * hg + 4];
            #pragma unroll
            for (int r = 0; r < 4; r++)
                #pragma unroll
                for (int j = 0; j < HGW; j++)
                    acc[r][j] = fmaf(av[r], wv[j], acc[r][j]);
        }
        #pragma unroll
        for (int r = 0; r < 4; r++) {
            unsigned short us[HGW];
            #pragma unroll
            for (int j = 0; j < HGW; j++)
                us[j] = f2bs(fmaxf(acc[r][j] + b1s[HGW * hg + j], 0.f));
            if constexpr (HGW == 8) {
                ushort4 u0; u0.x=us[0]; u0.y=us[1]; u0.z=us[2]; u0.w=us[3];
                ushort4 u1; u1.x=us[4]; u1.y=us[5]; u1.z=us[6]; u1.w=us[7];
                *(ushort4*)&h1[(4 * eg + r) * PH + 8 * hg] = u0;
                *(ushort4*)&h1[(4 * eg + r) * PH + 8 * hg + 4] = u1;
            } else {
                ushort4 u0; u0.x=us[0]; u0.y=us[1]; u0.z=us[2]; u0.w=us[3];
                *(ushort4*)&h1[(4 * eg + r) * PH + 4 * hg] = u0;
            }
        }
    }
    __syncthreads();

    {
        const int pt = tid & 31, cg = tid >> 5;
        float acc[4][CW];
        #pragma unroll
        for (int r = 0; r < 4; r++)
            #pragma unroll
            for (int c = 0; c < CW; c++) acc[r][c] = 0.f;

        if constexpr (H == 64) {
            #pragma unroll 2
            for (int kb = 0; kb < H / 8; kb++) {
                float hr[4][8];
                #pragma unroll
                for (int r = 0; r < 4; r++) {
                    const __hip_bfloat162* hp = (const __hip_bfloat162*)&h1[(4 * pt + r) * PH + 8 * kb];
                    float2 f0 = __bfloat1622float2(hp[0]);
                    float2 f1 = __bfloat1622float2(hp[1]);
                    float2 f2 = __bfloat1622float2(hp[2]);
                    float2 f3 = __bfloat1622float2(hp[3]);
                    hr[r][0]=f0.x; hr[r][1]=f0.y; hr[r][2]=f1.x; hr[r][3]=f1.y;
                    hr[r][4]=f2.x; hr[r][5]=f2.y; hr[r][6]=f3.x; hr[r][7]=f3.y;
                }
                #pragma unroll
                for (int j = 0; j < 8; j++) {
                    int k = 8 * kb + j;
                    float wv[CW];
                    *(float4*)&wv[0] = *(const float4*)&W2s[k * C + CW * cg];
                    if constexpr (CW == 8)
                        *(float4*)&wv[4] = *(const float4*)&W2s[k * C + CW * cg + 4];
                    #pragma unroll
                    for (int r = 0; r < 4; r++)
                        #pragma unroll
                        for (int c = 0; c < CW; c++)
                            acc[r][c] = fmaf(hr[r][j], wv[c], acc[r][c]);
                }
            }
        } else {
            #pragma unroll 4
            for (int k2 = 0; k2 < H; k2 += 2) {
                float2 hp[4];
                #pragma unroll
                for (int r = 0; r < 4; r++)
                    hp[r] = __bfloat1622float2(*(const __hip_bfloat162*)&h1[(4 * pt + r) * PH + k2]);
                float w0[CW], w1[CW];
                *(float4*)&w0[0] = *(const float4*)&W2s[k2 * C + CW * cg];
                *(float4*)&w1[0] = *(const float4*)&W2s[(k2 + 1) * C + CW * cg];
                #pragma unroll
                for (int r = 0; r < 4; r++)
                    #pragma unroll
                    for (int c = 0; c < CW; c++) {
                        acc[r][c] = fmaf(hp[r].x, w0[c], acc[r][c]);
                        acc[r][c] = fmaf(hp[r].y, w1[c], acc[r][c]);
                    }
            }
        }

        float res[CW];
        #pragma unroll
        for (int c = 0; c < CW; c++) {
            float m = fmaxf(fmaxf(acc[0][c], acc[1][c]), fmaxf(acc[2][c], acc[3][c]));
            res[c] = m + b2s[CW * cg + c];
        }
        if constexpr (sizeof(OT) == 4) {
            float4 v; v.x = res[0]; v.y = res[1]; v.z = res[2]; v.w = res[3];
            *(float4*)&out[(p0 + pt) * C + CW * cg] = v;
        } else {
            ushort4 u0, u1;
            u0.x=f2bs(res[0]); u0.y=f2bs(res[1]); u0.z=f2bs(res[2]); u0.w=f2bs(res[3]);
            u1.x=f2bs(res[4]); u1.y=f2bs(res[5]); u1.z=f2bs(res[6]); u1.w=f2bs(res[7]);
            *(ushort4*)&out[(p0 + pt) * C + CW * cg] = u0;
            *(ushort4*)&out[(p0 + pt) * C + CW * cg + 4] = u1;
        }
    }
}

// ---------------------------------------------------------------------------
// Weight prep for final MLP (unchanged)
// ---------------------------------------------------------------------------
__global__ void prep_kernel(const float* __restrict__ mW1, const float* __restrict__ mW2,
                            const float* __restrict__ mW3,
                            const float* __restrict__ mb1, const float* __restrict__ mb2,
                            const float* __restrict__ mb3,
                            __hip_bfloat16* __restrict__ WT1, __hip_bfloat16* __restrict__ WT2,
                            __hip_bfloat16* __restrict__ WT3, float* __restrict__ bp)
{
    const int t0 = blockIdx.x * blockDim.x + threadIdx.x;
    const int NT = gridDim.x * blockDim.x;
    for (int i = t0; i < 272 * 136; i += NT) {
        int n = i / 136, k = i - n * 136;
        WT1[i] = (n < 264 && k < 128) ? __float2bfloat16(mW1[(size_t)k * 264 + n]) : __float2bfloat16(0.f);
    }
    for (int i = t0; i < 272 * 296; i += NT) {
        int n = i / 296, k = i - n * 296;
        WT2[i] = (n < 264 && k < 264) ? __float2bfloat16(mW2[(size_t)k * 264 + n]) : __float2bfloat16(0.f);
        WT3[i] = (n < 264 && k < 264) ? __float2bfloat16(mW3[(size_t)k * 264 + n]) : __float2bfloat16(0.f);
    }
    for (int i = t0; i < 3 * 272; i += NT) {
        int l = i / 272, n = i - l * 272;
        const float* bsrc = (l == 0) ? mb1 : (l == 1) ? mb2 : mb3;
        bp[i] = (n < 264) ? bsrc[n] : 0.f;
    }
}

// ---------------------------------------------------------------------------
// Final MLP v3: direct-from-global weight frags + vectorized layer-4 tail
// (shift-based bf16 unpack; same fma summation order -> bit-identical).
// ---------------------------------------------------------------------------
__global__ __launch_bounds__(256, 3)
void mlp_kernel(const float* __restrict__ x1, const float* __restrict__ x2,
                const __hip_bfloat16* __restrict__ x3,
                const __hip_bfloat16* __restrict__ WT1, const __hip_bfloat16* __restrict__ WT2,
                const __hip_bfloat16* __restrict__ WT3, const float* __restrict__ bp,
                const float* __restrict__ mW4, const float* __restrict__ mb4,
                float* __restrict__ outp)
{
    constexpr int KPA = 296;
    __shared__ __hip_bfloat16 act[64 * KPA];    // 37.9 KB
    __shared__ __align__(16) float W4s[264 * 2 + 2];   // transposed: [c][k]
    __shared__ float lsm[64 * 2];

    const int tid = threadIdx.x;
    const int wv = tid >> 6, lane = tid & 63;
    const int rlane = lane & 15, ph = lane >> 4;
    const size_t row0 = (size_t)blockIdx.x * 64;

    for (int t = tid; t < 64 * KPA / 2; t += 256) ((unsigned int*)act)[t] = 0u;
    __syncthreads();
    for (int t = tid; t < 64 * 128; t += 256) {
        int r = t >> 7, c = t & 127;
        size_t g = row0 + r;
        __hip_bfloat16 v;
        if (c < 32)       v = __float2bfloat16(x1[g * 32 + c]);
        else if (c < 64)  v = __float2bfloat16(x2[g * 32 + (c - 32)]);
        else              v = x3[g * 64 + (c - 64)];
        act[r * KPA + c] = v;
    }
    for (int t = tid; t < 530; t += 256) {
        if (t < 528) { int c = t / 264, k2 = t - c * 264; W4s[t] = mW4[(size_t)k2 * 2 + c]; }
        else W4s[t] = mb4[t - 528];
    }
    __syncthreads();   // staging complete before layer-1 act reads

    const int ntc = (wv == 0) ? 5 : 4;
    v4f acc[5][4];

    auto layer = [&](const __hip_bfloat16* __restrict__ WT, int KP, int NK,
                     const float* __restrict__ bias) {
        #pragma unroll
        for (int i = 0; i < 5; i++)
            #pragma unroll
            for (int rt = 0; rt < 4; rt++) acc[i][rt] = (v4f){0.f, 0.f, 0.f, 0.f};

        for (int ks = 0; ks < NK; ks++) {
            v8bf bf[4];
            #pragma unroll
            for (int rt = 0; rt < 4; rt++) {
                uint4 u = *(const uint4*)&act[(rt * 16 + rlane) * KPA + ks * 32 + ph * 8];
                bf[rt] = __builtin_bit_cast(v8bf, u);
            }
            #pragma unroll
            for (int i = 0; i < 5; i++) {
                if (i < ntc) {
                    int nt = wv + 4 * i;
                    uint4 ua = *(const uint4*)(WT + (size_t)(nt * 16 + rlane) * KP + ks * 32 + ph * 8);
                    v8bf af = __builtin_bit_cast(v8bf, ua);
                    #pragma unroll
                    for (int rt = 0; rt < 4; rt++)
                        acc[i][rt] = __builtin_amdgcn_mfma_f32_16x16x32_bf16(af, bf[rt], acc[i][rt], 0, 0, 0);
                }
            }
        }
        __syncthreads();
        #pragma unroll
        for (int i = 0; i < 5; i++) {
            if (i < ntc) {
                int nt = wv + 4 * i;
                int col0 = nt * 16 + ph * 4;
                float4 bv = *(const float4*)&bias[col0];
                #pragma unroll
                for (int rt = 0; rt < 4; rt++) {
                    int row = rt * 16 + rlane;
                    ushort4 pk;
                    pk.x = f2bs(fmaxf(acc[i][rt][0] + bv.x, 0.f));
                    pk.y = f2bs(fmaxf(acc[i][rt][1] + bv.y, 0.f));
                    pk.z = f2bs(fmaxf(acc[i][rt][2] + bv.z, 0.f));
                    pk.w = f2bs(fmaxf(acc[i][rt][3] + bv.w, 0.f));
                    *(ushort4*)&act[row * KPA + col0] = pk;
                }
            }
        }
        __syncthreads();
    };

    layer(WT1, 136, 4, bp);
    layer(WT2, 296, 9, bp + 272);
    layer(WT3, 296, 9, bp + 544);

    // layer 4 (264 -> 2) + log_softmax, vectorized (same fma order)
    if (tid < 128) {
        int r = tid >> 1, c = tid & 1;
        const __hip_bfloat16* ap = &act[r * KPA];
        const float* wp = &W4s[c * 264];
        float s = 0.f;
        for (int k = 0; k < 264; k += 8) {
            uint4 u = *(const uint4*)&ap[k];
            float4 wa = *(const float4*)&wp[k];
            float4 wb = *(const float4*)&wp[k + 4];
            s = fmaf(bflo(u.x), wa.x, s); s = fmaf(bfhi(u.x), wa.y, s);
            s = fmaf(bflo(u.y), wa.z, s); s = fmaf(bfhi(u.y), wa.w, s);
            s = fmaf(bflo(u.z), wb.x, s); s = fmaf(bfhi(u.z), wb.y, s);
            s = fmaf(bflo(u.w), wb.z, s); s = fmaf(bfhi(u.w), wb.w, s);
        }
        lsm[tid] = s + W4s[528 + c];
    }
    __syncthreads();
    if (tid < 64) {
        float l0 = lsm[tid * 2 + 0], l1 = lsm[tid * 2 + 1];
        float m = fmaxf(l0, l1);
        float lse = m + logf(expf(l0 - m) + expf(l1 - m));
        float2 o; o.x = l0 - lse; o.y = l1 - lse;
        *(float2*)&outp[(row0 + tid) * 2] = o;
    }
}

// ---------------------------------------------------------------------------
extern "C" void kernel_launch(void* const* d_in, const int* in_sizes, int n_in,
                              void* d_out, int out_size, void* d_ws, size_t ws_size,
                              hipStream_t stream)
{
    const float* x    = (const float*)d_in[0];
    const float* c1W1 = (const float*)d_in[2];
    const float* c1b1 = (const float*)d_in[3];
    const float* c1W2 = (const float*)d_in[4];
    const float* c1b2 = (const float*)d_in[5];
    const float* c2W1 = (const float*)d_in[6];
    const float* c2b1 = (const float*)d_in[7];
    const float* c2W2 = (const float*)d_in[8];
    const float* c2b2 = (const float*)d_in[9];
    const float* c3W1 = (const float*)d_in[10];
    const float* c3b1 = (const float*)d_in[11];
    const float* c3W2 = (const float*)d_in[12];
    const float* c3b2 = (const float*)d_in[13];
    const float* mW1  = (const float*)d_in[14];
    const float* mb1  = (const float*)d_in[15];
    const float* mW2  = (const float*)d_in[16];
    const float* mb2  = (const float*)d_in[17];
    const float* mW3  = (const float*)d_in[18];
    const float* mb3  = (const float*)d_in[19];
    const float* mW4  = (const float*)d_in[20];
    const float* mb4  = (const float*)d_in[21];

    // workspace carve (~70 MB)
    float* x1 = (float*)d_ws;                                        // [N,32] f32
    float* x2 = x1 + (size_t)NROWS * 32;                             // [N,32] f32
    __hip_bfloat16* x3 = (__hip_bfloat16*)(x2 + (size_t)NROWS * 32); // [N,64] bf16
    int* nidx = (int*)(x3 + (size_t)NROWS * 64);                     // [N,4] i32
    __hip_bfloat16* WT1 = (__hip_bfloat16*)(nidx + (size_t)NROWS * 4);
    __hip_bfloat16* WT2 = WT1 + 272 * 136;
    __hip_bfloat16* WT3 = WT2 + 272 * 296;
    float* bp = (float*)(WT3 + 272 * 296);                           // [3][272] f32
    __hip_bfloat16* xph = (__hip_bfloat16*)(bp + 3 * 272);           // [N,32] bf16
    __hip_bfloat16* xpl = xph + (size_t)NROWS * 32;                  // [N,32] bf16
    float* sqw = (float*)(xpl + (size_t)NROWS * 32);                 // [N] f32

    prep_kernel<<<dim3(512), 256, 0, stream>>>(mW1, mW2, mW3, mb1, mb2, mb3,
                                               WT1, WT2, WT3, bp);

    dim3 kgrid(PP / 64, BB);
    dim3 pgrid(NROWS * 4 / 256);
    dim3 egrid(NROWS / 32);

    pack_kernel<<<pgrid, 256, 0, stream>>>(x, 1, xph, xpl, sqw);
    knn_mfma<<<kgrid, 256, 0, stream>>>(xph, xpl, sqw, nidx);
    edge_kernel<1, 32, 32, float><<<egrid, 256, 0, stream>>>(x, nidx, c1W1, c1b1, c1W2, c1b2, x1);

    pack_kernel<<<pgrid, 256, 0, stream>>>(x1, 32, xph, xpl, sqw);
    knn_mfma<<<kgrid, 256, 0, stream>>>(xph, xpl, sqw, nidx);
    edge_kernel<32, 32, 32, float><<<egrid, 256, 0, stream>>>(x1, nidx, c2W1, c2b1, c2W2, c2b2, x2);

    pack_kernel<<<pgrid, 256, 0, stream>>>(x2, 32, xph, xpl, sqw);
    knn_mfma<<<kgrid, 256, 0, stream>>>(xph, xpl, sqw, nidx);
    edge_kernel<32, 64, 64, __hip_bfloat16><<<egrid, 256, 0, stream>>>(x2, nidx, c3W1, c3b1, c3W2, c3b2, x3);

    mlp_kernel<<<dim3(NROWS / 64), 256, 0, stream>>>(x1, x2, x3, WT1, WT2, WT3, bp,
                                                     mW4, mb4, (float*)d_out);
}

// Round 8
// 678.183 us; speedup vs baseline: 9.9996x; 1.1808x over previous
//
#include <hip/hip_runtime.h>
#include <hip/hip_bf16.h>
#include <float.h>
#include <math.h>

#define BB 128
#define PP 1024
#define KNN 4
#define NROWS (BB * PP)

typedef __bf16 v8bf __attribute__((ext_vector_type(8)));
typedef float  v4f  __attribute__((ext_vector_type(4)));

__device__ inline unsigned short f2bs(float f) {
    __hip_bfloat16 h = __float2bfloat16(f);
    return *(unsigned short*)&h;
}
__device__ inline unsigned packbf2(float a, float b) {
    return (unsigned)f2bs(a) | ((unsigned)f2bs(b) << 16);
}
// bf16 pair (packed in u32) -> two f32, bit-exact
__device__ inline float bflo(unsigned u) { return __builtin_bit_cast(float, u << 16); }
__device__ inline float bfhi(unsigned u) { return __builtin_bit_cast(float, u & 0xFFFF0000u); }

// ---------------------------------------------------------------------------
// Pack kernel: split fp32 rows into hi/lo bf16 padded to 32 dims + row sq.
// ---------------------------------------------------------------------------
__global__ __launch_bounds__(256)
void pack_kernel(const float* __restrict__ src, int D,
                 __hip_bfloat16* __restrict__ xh, __hip_bfloat16* __restrict__ xl,
                 float* __restrict__ sq)
{
    const int t = blockIdx.x * 256 + threadIdx.x;     // t < NROWS*4
    const int row = t >> 2, part = t & 3;
    float v[8];
    #pragma unroll
    for (int u = 0; u < 8; u++) {
        int d = part * 8 + u;
        v[u] = (d < D) ? src[(size_t)row * D + d] : 0.f;
    }
    float s = 0.f;
    unsigned int hw[4], lw[4];
    #pragma unroll
    for (int w = 0; w < 4; w++) {
        unsigned short h2[2], l2[2];
        #pragma unroll
        for (int e = 0; e < 2; e++) {
            float x = v[2 * w + e];
            __hip_bfloat16 hb = __float2bfloat16(x);
            float hf = __bfloat162float(hb);
            __hip_bfloat16 lb = __float2bfloat16(x - hf);
            h2[e] = *(unsigned short*)&hb;
            l2[e] = *(unsigned short*)&lb;
            s = fmaf(x, x, s);
        }
        hw[w] = (unsigned int)h2[0] | ((unsigned int)h2[1] << 16);
        lw[w] = (unsigned int)l2[0] | ((unsigned int)l2[1] << 16);
    }
    s += __shfl_xor(s, 1);
    s += __shfl_xor(s, 2);
    uint4 hv; hv.x = hw[0]; hv.y = hw[1]; hv.z = hw[2]; hv.w = hw[3];
    uint4 lv; lv.x = lw[0]; lv.y = lw[1]; lv.z = lw[2]; lv.w = lw[3];
    *(uint4*)&xh[(size_t)row * 32 + part * 8] = hv;
    *(uint4*)&xl[(size_t)row * 32 + part * 8] = lv;
    if (part == 0) sq[row] = s;
}

// ---------------------------------------------------------------------------
// MFMA kNN (unchanged from round 7 — passing)
// ---------------------------------------------------------------------------
__global__ __launch_bounds__(256, 4)
void knn_mfma(const __hip_bfloat16* __restrict__ xh, const __hip_bfloat16* __restrict__ xl,
              const float* __restrict__ sq, int* __restrict__ nidx)
{
    constexpr int PITCH = 129;
    __shared__ __align__(16) float sc[64 * PITCH];
    unsigned long long* cand64 = (unsigned long long*)sc;

    const int tid = threadIdx.x;
    const int wv = tid >> 6, lane = tid & 63;
    const int lr = lane & 15, lq = lane >> 4;
    const int b = blockIdx.y, i0 = blockIdx.x * 64;
    const size_t Rb = (size_t)b * PP;

    v8bf ah[4], al[4];
    #pragma unroll
    for (int it = 0; it < 4; it++) {
        size_t g = Rb + i0 + it * 16 + lr;
        ah[it] = __builtin_bit_cast(v8bf, *(const uint4*)(xh + g * 32 + lq * 8));
        al[it] = __builtin_bit_cast(v8bf, *(const uint4*)(xl + g * 32 + lq * 8));
    }

    const int r = tid & 63, qt = tid >> 6;
    unsigned long long k0 = ~0ull, k1 = ~0ull, k2 = ~0ull, k3 = ~0ull;

    for (int ch = 0; ch < 8; ch++) {
        #pragma unroll
        for (int jt2 = 0; jt2 < 2; jt2++) {
            const int tl = wv * 2 + jt2;
            const size_t gj = Rb + ch * 128 + tl * 16 + lr;
            v8bf bh = __builtin_bit_cast(v8bf, *(const uint4*)(xh + gj * 32 + lq * 8));
            v8bf bl = __builtin_bit_cast(v8bf, *(const uint4*)(xl + gj * 32 + lq * 8));
            const float sqv = sq[gj];
            #pragma unroll
            for (int it = 0; it < 4; it++) {
                v4f a = (v4f){0.f, 0.f, 0.f, 0.f};
                a = __builtin_amdgcn_mfma_f32_16x16x32_bf16(al[it], bl, a, 0, 0, 0);
                a = __builtin_amdgcn_mfma_f32_16x16x32_bf16(al[it], bh, a, 0, 0, 0);
                a = __builtin_amdgcn_mfma_f32_16x16x32_bf16(ah[it], bl, a, 0, 0, 0);
                a = __builtin_amdgcn_mfma_f32_16x16x32_bf16(ah[it], bh, a, 0, 0, 0);
                #pragma unroll
                for (int m = 0; m < 4; m++)
                    sc[(it * 16 + lq * 4 + m) * PITCH + tl * 16 + lr] =
                        fmaf(-2.f, a[m], sqv);
            }
        }
        __syncthreads();
        {
            const float* rowp = &sc[r * PITCH + qt * 32];
            const int jb = ch * 128 + qt * 32;
            #pragma unroll
            for (int u = 0; u < 32; u++) {
                float s = rowp[u];
                unsigned ub = __builtin_bit_cast(unsigned, s);
                unsigned mm = (unsigned)((int)ub >> 31);
                unsigned ord = ub ^ (mm | 0x80000000u);
                unsigned long long key =
                    ((unsigned long long)ord << 32) | (unsigned)(jb + u);
                unsigned long long t; bool c;
                c = key < k0; t = c ? key : k0; key = c ? k0 : key; k0 = t;
                c = key < k1; t = c ? key : k1; key = c ? k1 : key; k1 = t;
                c = key < k2; t = c ? key : k2; key = c ? k2 : key; k2 = t;
                c = key < k3; k3 = c ? key : k3;
            }
        }
        __syncthreads();
    }

    cand64[(qt * 4 + 0) * 64 + r] = k0;
    cand64[(qt * 4 + 1) * 64 + r] = k1;
    cand64[(qt * 4 + 2) * 64 + r] = k2;
    cand64[(qt * 4 + 3) * 64 + r] = k3;
    __syncthreads();

    if (tid < 64) {
        unsigned long long m0 = ~0ull, m1 = ~0ull, m2 = ~0ull, m3 = ~0ull;
        #pragma unroll
        for (int s2 = 0; s2 < 16; s2++) {
            unsigned long long key = cand64[s2 * 64 + tid];
            unsigned long long t; bool c;
            c = key < m0; t = c ? key : m0; key = c ? m0 : key; m0 = t;
            c = key < m1; t = c ? key : m1; key = c ? m1 : key; m1 = t;
            c = key < m2; t = c ? key : m2; key = c ? m2 : key; m2 = t;
            c = key < m3; m3 = c ? key : m3;
        }
        const int base = (int)Rb;
        int* op = nidx + (size_t)(Rb + i0 + tid) * KNN;
        op[0] = base + (int)((unsigned)m0 & 1023u);
        op[1] = base + (int)((unsigned)m1 & 1023u);
        op[2] = base + (int)((unsigned)m2 & 1023u);
        op[3] = base + (int)((unsigned)m3 & 1023u);
    }
}

// ---------------------------------------------------------------------------
// Edge-MLP v2 (MFMA): block = 32 points (128 edges), 256 threads / 4 waves.
// GEMM1: h1 = [xi|xj] @ EW1^T  (EW1 = [[W1a-W1b];[W1b]] pre-transposed bf16,
//        B-frags read directly from global, L2-resident).
// C-layout trick: edges ride the quad*4+reg dim -> in GEMM2's D-frag each
// lane's 4 regs are the 4 edges of one point: max-agg = 3 v_max in-register.
// ---------------------------------------------------------------------------
template<int D, int H, int C, typename OT>
__global__ __launch_bounds__(256, 4)
void edge_mfma(const float* __restrict__ x, const int* __restrict__ nidx,
               const __hip_bfloat16* __restrict__ EW1, const __hip_bfloat16* __restrict__ EW2,
               const float* __restrict__ b1g, const float* __restrict__ b2g,
               OT* __restrict__ out)
{
    constexpr int PT = 32, NE = 128;
    constexpr int TDP = (D == 1) ? 32 : 64;   // padded K of GEMM1
    constexpr int DP  = TDP / 2;              // xj offset
    constexpr int XP  = TDP + 8;              // LDS pitch (16B aligned, 2-way reads)
    constexpr int HP  = H + 8;
    constexpr int NT1 = H / 16, NT2 = C / 16;
    constexpr int KS1 = TDP / 32, KS2 = H / 32;

    __shared__ __hip_bfloat16 xe[NE * XP];
    __shared__ __hip_bfloat16 h1b[NE * HP];
    __shared__ float b1s[H], b2s[C];
    __shared__ int nid[NE];

    const int tid = threadIdx.x;
    const int wv = tid >> 6, lane = tid & 63;
    const int lr = lane & 15, q = lane >> 4;
    const int p0 = blockIdx.x * PT;

    if (tid < NE) nid[tid] = nidx[(size_t)p0 * KNN + tid];
    if (tid < H) b1s[tid] = b1g[tid];
    if (tid < C) b2s[tid] = b2g[tid];
    if constexpr (D == 1) {
        // zero-fill: padded k-slots meet zero EW1 rows, but must not be NaN
        for (int t = tid; t < NE * XP / 2; t += 256) ((unsigned*)xe)[t] = 0u;
    }
    __syncthreads();

    // gather edge features: thread = (edge, half); half0 = xi, half1 = xj
    {
        const int e = tid & 127, part = tid >> 7;
        if constexpr (D == 1) {
            float v = (part == 0) ? x[p0 + (e >> 2)] : x[nid[e]];
            xe[e * XP + part * DP] = __float2bfloat16(v);
        } else {
            const float* src = (part == 0) ? (x + (size_t)(p0 + (e >> 2)) * D)
                                           : (x + (size_t)nid[e] * D);
            const int koff = part * DP;
            #pragma unroll
            for (int s = 0; s < D / 8; s++) {
                float4 f0 = *(const float4*)&src[s * 8];
                float4 f1 = *(const float4*)&src[s * 8 + 4];
                uint4 uv;
                uv.x = packbf2(f0.x, f0.y); uv.y = packbf2(f0.z, f0.w);
                uv.z = packbf2(f1.x, f1.y); uv.w = packbf2(f1.z, f1.w);
                *(uint4*)&xe[e * XP + koff + s * 8] = uv;
            }
        }
    }
    __syncthreads();

    // ---- GEMM1: arg0 = xe (edges -> quad*4+reg in D), arg1 = EW1 global ----
    v4f acc1[2][NT1];
    #pragma unroll
    for (int mi = 0; mi < 2; mi++)
        #pragma unroll
        for (int nt = 0; nt < NT1; nt++) acc1[mi][nt] = (v4f){0.f, 0.f, 0.f, 0.f};

    #pragma unroll
    for (int ks = 0; ks < KS1; ks++) {
        v8bf a[2];
        #pragma unroll
        for (int mi = 0; mi < 2; mi++)
            a[mi] = __builtin_bit_cast(v8bf,
                *(const uint4*)&xe[((wv * 2 + mi) * 16 + lr) * XP + ks * 32 + q * 8]);
        v8bf b[NT1];
        #pragma unroll
        for (int nt = 0; nt < NT1; nt++)
            b[nt] = __builtin_bit_cast(v8bf,
                *(const uint4*)(EW1 + (size_t)(nt * 16 + lr) * TDP + ks * 32 + q * 8));
        #pragma unroll
        for (int mi = 0; mi < 2; mi++)
            #pragma unroll
            for (int nt = 0; nt < NT1; nt++)
                acc1[mi][nt] = __builtin_amdgcn_mfma_f32_16x16x32_bf16(a[mi], b[nt], acc1[mi][nt], 0, 0, 0);
    }
    // epilogue: bias + relu -> h1b[edge][h] (bf16)
    #pragma unroll
    for (int mi = 0; mi < 2; mi++)
        #pragma unroll
        for (int nt = 0; nt < NT1; nt++) {
            const int col = nt * 16 + lr;
            const float bias = b1s[col];
            #pragma unroll
            for (int m = 0; m < 4; m++) {
                int row = (wv * 2 + mi) * 16 + q * 4 + m;
                h1b[row * HP + col] = __float2bfloat16(fmaxf(acc1[mi][nt][m] + bias, 0.f));
            }
        }
    __syncthreads();

    // ---- GEMM2: arg0 = h1 (edges -> quad*4+reg), arg1 = EW2 global ----
    v4f acc2[2][NT2];
    #pragma unroll
    for (int mi = 0; mi < 2; mi++)
        #pragma unroll
        for (int nt = 0; nt < NT2; nt++) acc2[mi][nt] = (v4f){0.f, 0.f, 0.f, 0.f};

    #pragma unroll
    for (int ks = 0; ks < KS2; ks++) {
        v8bf a[2];
        #pragma unroll
        for (int mi = 0; mi < 2; mi++)
            a[mi] = __builtin_bit_cast(v8bf,
                *(const uint4*)&h1b[((wv * 2 + mi) * 16 + lr) * HP + ks * 32 + q * 8]);
        v8bf b[NT2];
        #pragma unroll
        for (int nt = 0; nt < NT2; nt++)
            b[nt] = __builtin_bit_cast(v8bf,
                *(const uint4*)(EW2 + (size_t)(nt * 16 + lr) * H + ks * 32 + q * 8));
        #pragma unroll
        for (int mi = 0; mi < 2; mi++)
            #pragma unroll
            for (int nt = 0; nt < NT2; nt++)
                acc2[mi][nt] = __builtin_amdgcn_mfma_f32_16x16x32_bf16(a[mi], b[nt], acc2[mi][nt], 0, 0, 0);
    }
    // epilogue: max over the 4 regs (= 4 edges of point) + bias, store
    #pragma unroll
    for (int mi = 0; mi < 2; mi++)
        #pragma unroll
        for (int nt = 0; nt < NT2; nt++) {
            const int c = nt * 16 + lr;
            float v = fmaxf(fmaxf(acc2[mi][nt][0], acc2[mi][nt][1]),
                            fmaxf(acc2[mi][nt][2], acc2[mi][nt][3])) + b2s[c];
            const int p = p0 + (wv * 2 + mi) * 4 + q;
            if constexpr (sizeof(OT) == 4) out[(size_t)p * C + c] = v;
            else                           out[(size_t)p * C + c] = __float2bfloat16(v);
        }
}

// ---------------------------------------------------------------------------
// Weight prep: final-MLP transposes (unchanged) + edge-conv weights:
// EW1_l = [[W1a-W1b];[W1b]] zero-padded, transposed to [h][k] bf16;
// EW2_l = W2 transposed to [c][h] bf16.
// ---------------------------------------------------------------------------
__global__ void prep_kernel(const float* __restrict__ mW1, const float* __restrict__ mW2,
                            const float* __restrict__ mW3,
                            const float* __restrict__ mb1, const float* __restrict__ mb2,
                            const float* __restrict__ mb3,
                            const float* __restrict__ c1W1, const float* __restrict__ c1W2,
                            const float* __restrict__ c2W1, const float* __restrict__ c2W2,
                            const float* __restrict__ c3W1, const float* __restrict__ c3W2,
                            __hip_bfloat16* __restrict__ WT1, __hip_bfloat16* __restrict__ WT2,
                            __hip_bfloat16* __restrict__ WT3, float* __restrict__ bp,
                            __hip_bfloat16* __restrict__ E11, __hip_bfloat16* __restrict__ E12,
                            __hip_bfloat16* __restrict__ E13,
                            __hip_bfloat16* __restrict__ E21, __hip_bfloat16* __restrict__ E22,
                            __hip_bfloat16* __restrict__ E23)
{
    const int t0 = blockIdx.x * blockDim.x + threadIdx.x;
    const int NT = gridDim.x * blockDim.x;
    for (int i = t0; i < 272 * 136; i += NT) {
        int n = i / 136, k = i - n * 136;
        WT1[i] = (n < 264 && k < 128) ? __float2bfloat16(mW1[(size_t)k * 264 + n]) : __float2bfloat16(0.f);
    }
    for (int i = t0; i < 272 * 296; i += NT) {
        int n = i / 296, k = i - n * 296;
        WT2[i] = (n < 264 && k < 264) ? __float2bfloat16(mW2[(size_t)k * 264 + n]) : __float2bfloat16(0.f);
        WT3[i] = (n < 264 && k < 264) ? __float2bfloat16(mW3[(size_t)k * 264 + n]) : __float2bfloat16(0.f);
    }
    for (int i = t0; i < 3 * 272; i += NT) {
        int l = i / 272, n = i - l * 272;
        const float* bsrc = (l == 0) ? mb1 : (l == 1) ? mb2 : mb3;
        bp[i] = (n < 264) ? bsrc[n] : 0.f;
    }
    // conv1: D=1,H=32,TDP=32,DP=16 — E11[h][k], pitch 32
    for (int i = t0; i < 32 * 32; i += NT) {
        int h = i >> 5, k = i & 31;
        float v = (k == 0) ? (c1W1[h] - c1W1[32 + h]) : (k == 16 ? c1W1[32 + h] : 0.f);
        E11[i] = __float2bfloat16(v);
    }
    // conv2: D=32,H=32,TDP=64 — E12[h][k], pitch 64
    for (int i = t0; i < 32 * 64; i += NT) {
        int h = i >> 6, k = i & 63;
        float v = (k < 32) ? (c2W1[k * 32 + h] - c2W1[(k + 32) * 32 + h]) : c2W1[k * 32 + h];
        E12[i] = __float2bfloat16(v);
    }
    // conv3: D=32,H=64,TDP=64 — E13[h][k], pitch 64
    for (int i = t0; i < 64 * 64; i += NT) {
        int h = i >> 6, k = i & 63;
        float v = (k < 32) ? (c3W1[k * 64 + h] - c3W1[(k + 32) * 64 + h]) : c3W1[k * 64 + h];
        E13[i] = __float2bfloat16(v);
    }
    // EW2: [c][h]
    for (int i = t0; i < 32 * 32; i += NT) {
        int c = i >> 5, h = i & 31;
        E21[i] = __float2bfloat16(c1W2[h * 32 + c]);
        E22[i] = __float2bfloat16(c2W2[h * 32 + c]);
    }
    for (int i = t0; i < 64 * 64; i += NT) {
        int c = i >> 6, h = i & 63;
        E23[i] = __float2bfloat16(c3W2[h * 64 + c]);
    }
}

// ---------------------------------------------------------------------------
// Final MLP v3 (unchanged from round 7 — passing)
// ---------------------------------------------------------------------------
__global__ __launch_bounds__(256, 3)
void mlp_kernel(const float* __restrict__ x1, const float* __restrict__ x2,
                const __hip_bfloat16* __restrict__ x3,
                const __hip_bfloat16* __restrict__ WT1, const __hip_bfloat16* __restrict__ WT2,
                const __hip_bfloat16* __restrict__ WT3, const float* __restrict__ bp,
                const float* __restrict__ mW4, const float* __restrict__ mb4,
                float* __restrict__ outp)
{
    constexpr int KPA = 296;
    __shared__ __hip_bfloat16 act[64 * KPA];
    __shared__ __align__(16) float W4s[264 * 2 + 2];
    __shared__ float lsm[64 * 2];

    const int tid = threadIdx.x;
    const int wv = tid >> 6, lane = tid & 63;
    const int rlane = lane & 15, ph = lane >> 4;
    const size_t row0 = (size_t)blockIdx.x * 64;

    for (int t = tid; t < 64 * KPA / 2; t += 256) ((unsigned int*)act)[t] = 0u;
    __syncthreads();
    for (int t = tid; t < 64 * 128; t += 256) {
        int r = t >> 7, c = t & 127;
        size_t g = row0 + r;
        __hip_bfloat16 v;
        if (c < 32)       v = __float2bfloat16(x1[g * 32 + c]);
        else if (c < 64)  v = __float2bfloat16(x2[g * 32 + (c - 32)]);
        else              v = x3[g * 64 + (c - 64)];
        act[r * KPA + c] = v;
    }
    for (int t = tid; t < 530; t += 256) {
        if (t < 528) { int c = t / 264, k2 = t - c * 264; W4s[t] = mW4[(size_t)k2 * 2 + c]; }
        else W4s[t] = mb4[t - 528];
    }
    __syncthreads();

    const int ntc = (wv == 0) ? 5 : 4;
    v4f acc[5][4];

    auto layer = [&](const __hip_bfloat16* __restrict__ WT, int KP, int NK,
                     const float* __restrict__ bias) {
        #pragma unroll
        for (int i = 0; i < 5; i++)
            #pragma unroll
            for (int rt = 0; rt < 4; rt++) acc[i][rt] = (v4f){0.f, 0.f, 0.f, 0.f};

        for (int ks = 0; ks < NK; ks++) {
            v8bf bf[4];
            #pragma unroll
            for (int rt = 0; rt < 4; rt++) {
                uint4 u = *(const uint4*)&act[(rt * 16 + rlane) * KPA + ks * 32 + ph * 8];
                bf[rt] = __builtin_bit_cast(v8bf, u);
            }
            #pragma unroll
            for (int i = 0; i < 5; i++) {
                if (i < ntc) {
                    int nt = wv + 4 * i;
                    uint4 ua = *(const uint4*)(WT + (size_t)(nt * 16 + rlane) * KP + ks * 32 + ph * 8);
                    v8bf af = __builtin_bit_cast(v8bf, ua);
                    #pragma unroll
                    for (int rt = 0; rt < 4; rt++)
                        acc[i][rt] = __builtin_amdgcn_mfma_f32_16x16x32_bf16(af, bf[rt], acc[i][rt], 0, 0, 0);
                }
            }
        }
        __syncthreads();
        #pragma unroll
        for (int i = 0; i < 5; i++) {
            if (i < ntc) {
                int nt = wv + 4 * i;
                int col0 = nt * 16 + ph * 4;
                float4 bv = *(const float4*)&bias[col0];
                #pragma unroll
                for (int rt = 0; rt < 4; rt++) {
                    int row = rt * 16 + rlane;
                    ushort4 pk;
                    pk.x = f2bs(fmaxf(acc[i][rt][0] + bv.x, 0.f));
                    pk.y = f2bs(fmaxf(acc[i][rt][1] + bv.y, 0.f));
                    pk.z = f2bs(fmaxf(acc[i][rt][2] + bv.z, 0.f));
                    pk.w = f2bs(fmaxf(acc[i][rt][3] + bv.w, 0.f));
                    *(ushort4*)&act[row * KPA + col0] = pk;
                }
            }
        }
        __syncthreads();
    };

    layer(WT1, 136, 4, bp);
    layer(WT2, 296, 9, bp + 272);
    layer(WT3, 296, 9, bp + 544);

    if (tid < 128) {
        int r = tid >> 1, c = tid & 1;
        const __hip_bfloat16* ap = &act[r * KPA];
        const float* wp = &W4s[c * 264];
        float s = 0.f;
        for (int k = 0; k < 264; k += 8) {
            uint4 u = *(const uint4*)&ap[k];
            float4 wa = *(const float4*)&wp[k];
            float4 wb = *(const float4*)&wp[k + 4];
            s = fmaf(bflo(u.x), wa.x, s); s = fmaf(bfhi(u.x), wa.y, s);
            s = fmaf(bflo(u.y), wa.z, s); s = fmaf(bfhi(u.y), wa.w, s);
            s = fmaf(bflo(u.z), wb.x, s); s = fmaf(bfhi(u.z), wb.y, s);
            s = fmaf(bflo(u.w), wb.z, s); s = fmaf(bfhi(u.w), wb.w, s);
        }
        lsm[tid] = s + W4s[528 + c];
    }
    __syncthreads();
    if (tid < 64) {
        float l0 = lsm[tid * 2 + 0], l1 = lsm[tid * 2 + 1];
        float m = fmaxf(l0, l1);
        float lse = m + logf(expf(l0 - m) + expf(l1 - m));
        float2 o; o.x = l0 - lse; o.y = l1 - lse;
        *(float2*)&outp[(row0 + tid) * 2] = o;
    }
}

// ---------------------------------------------------------------------------
extern "C" void kernel_launch(void* const* d_in, const int* in_sizes, int n_in,
                              void* d_out, int out_size, void* d_ws, size_t ws_size,
                              hipStream_t stream)
{
    const float* x    = (const float*)d_in[0];
    const float* c1W1 = (const float*)d_in[2];
    const float* c1b1 = (const float*)d_in[3];
    const float* c1W2 = (const float*)d_in[4];
    const float* c1b2 = (const float*)d_in[5];
    const float* c2W1 = (const float*)d_in[6];
    const float* c2b1 = (const float*)d_in[7];
    const float* c2W2 = (const float*)d_in[8];
    const float* c2b2 = (const float*)d_in[9];
    const float* c3W1 = (const float*)d_in[10];
    const float* c3b1 = (const float*)d_in[11];
    const float* c3W2 = (const float*)d_in[12];
    const float* c3b2 = (const float*)d_in[13];
    const float* mW1  = (const float*)d_in[14];
    const float* mb1  = (const float*)d_in[15];
    const float* mW2  = (const float*)d_in[16];
    const float* mb2  = (const float*)d_in[17];
    const float* mW3  = (const float*)d_in[18];
    const float* mb3  = (const float*)d_in[19];
    const float* mW4  = (const float*)d_in[20];
    const float* mb4  = (const float*)d_in[21];

    // workspace carve (~70 MB)
    float* x1 = (float*)d_ws;                                        // [N,32] f32
    float* x2 = x1 + (size_t)NROWS * 32;                             // [N,32] f32
    __hip_bfloat16* x3 = (__hip_bfloat16*)(x2 + (size_t)NROWS * 32); // [N,64] bf16
    int* nidx = (int*)(x3 + (size_t)NROWS * 64);                     // [N,4] i32
    __hip_bfloat16* WT1 = (__hip_bfloat16*)(nidx + (size_t)NROWS * 4);
    __hip_bfloat16* WT2 = WT1 + 272 * 136;
    __hip_bfloat16* WT3 = WT2 + 272 * 296;
    float* bp = (float*)(WT3 + 272 * 296);                           // [3][272] f32
    __hip_bfloat16* xph = (__hip_bfloat16*)(bp + 3 * 272);           // [N,32] bf16
    __hip_bfloat16* xpl = xph + (size_t)NROWS * 32;                  // [N,32] bf16
    float* sqw = (float*)(xpl + (size_t)NROWS * 32);                 // [N] f32
    __hip_bfloat16* E11 = (__hip_bfloat16*)(sqw + NROWS);            // [32][32]
    __hip_bfloat16* E12 = E11 + 32 * 32;                             // [32][64]
    __hip_bfloat16* E13 = E12 + 32 * 64;                             // [64][64]
    __hip_bfloat16* E21 = E13 + 64 * 64;                             // [32][32]
    __hip_bfloat16* E22 = E21 + 32 * 32;                             // [32][32]
    __hip_bfloat16* E23 = E22 + 32 * 32;                             // [64][64]

    prep_kernel<<<dim3(512), 256, 0, stream>>>(mW1, mW2, mW3, mb1, mb2, mb3,
                                               c1W1, c1W2, c2W1, c2W2, c3W1, c3W2,
                                               WT1, WT2, WT3, bp,
                                               E11, E12, E13, E21, E22, E23);

    dim3 kgrid(PP / 64, BB);
    dim3 pgrid(NROWS * 4 / 256);
    dim3 egrid(NROWS / 32);

    pack_kernel<<<pgrid, 256, 0, stream>>>(x, 1, xph, xpl, sqw);
    knn_mfma<<<kgrid, 256, 0, stream>>>(xph, xpl, sqw, nidx);
    edge_mfma<1, 32, 32, float><<<egrid, 256, 0, stream>>>(x, nidx, E11, E21, c1b1, c1b2, x1);

    pack_kernel<<<pgrid, 256, 0, stream>>>(x1, 32, xph, xpl, sqw);
    knn_mfma<<<kgrid, 256, 0, stream>>>(xph, xpl, sqw, nidx);
    edge_mfma<32, 32, 32, float><<<egrid, 256, 0, stream>>>(x1, nidx, E12, E22, c2b1, c2b2, x2);

    pack_kernel<<<pgrid, 256, 0, stream>>>(x2, 32, xph, xpl, sqw);
    knn_mfma<<<kgrid, 256, 0, stream>>>(xph, xpl, sqw, nidx);
    edge_mfma<32, 64, 64, __hip_bfloat16><<<egrid, 256, 0, stream>>>(x2, nidx, E13, E23, c3b1, c3b2, x3);

    mlp_kernel<<<dim3(NROWS / 64), 256, 0, stream>>>(x1, x2, x3, WT1, WT2, WT3, bp,
                                                     mW4, mb4, (float*)d_out);
}